// Round 9
// baseline (1859.275 us; speedup 1.0000x reference)
//
#include <hip/hip_runtime.h>
#include <math.h>

#define NPTS 2048
#define NB 8
#define BN 16384   // NB*NPTS
#define KNN 16

typedef _Float16 half4 __attribute__((ext_vector_type(4)));
typedef _Float16 half8 __attribute__((ext_vector_type(8)));
typedef float floatx16 __attribute__((ext_vector_type(16)));

// ---------------- fused sq + prep: sq | Wcat/bcat | W2 hi/lo split (transposed) ------
__global__ __launch_bounds__(256) void sqprep_kernel(const float* __restrict__ X,
                                                     float* __restrict__ SQ,
                                                     const float* __restrict__ W1,
                                                     const float* __restrict__ b1,
                                                     float* __restrict__ Wcat,
                                                     float* __restrict__ bcat,
                                                     int din, int d2,
                                                     const float* __restrict__ W2,
                                                     _Float16* __restrict__ W2H,
                                                     _Float16* __restrict__ W2L,
                                                     int dout, int pb) {
    const int bid = blockIdx.x;
    if (bid < BN / 256) {
        int g = bid * 256 + threadIdx.x;
        const float* row = X + (size_t)g * din;
        float s = 0.f;
        for (int d = 0; d < din; ++d) s = fmaf(row[d], row[d], s);
        SQ[g] = s;
    } else if (bid < BN / 256 + pb) {
        int n4 = 2 * d2;
        int total = din * n4;
        int i = (bid - BN / 256) * 256 + threadIdx.x;
        if (i < total) {
            int d = i / n4, c = i - d * n4;
            float v;
            if (c < d2) v = W1[d * d2 + c] - W1[(din + d) * d2 + c];
            else        v = W1[(din + d) * d2 + (c - d2)];
            Wcat[i] = v;
        }
        if (i < n4) bcat[i] = (i < d2) ? b1[i] : 0.f;
    } else {
        // W2 split: W2 is [d2][dout] fp32 -> W2H/W2L [dout][d2] f16 (hi + residual lo)
        int i = (bid - BN / 256 - pb) * 256 + threadIdx.x;
        if (i < d2 * dout) {
            int k = i / dout, c = i - k * dout;
            float wv = W2[i];
            _Float16 hv = (_Float16)wv;
            float rv = wv - (float)hv;
            W2H[(size_t)c * d2 + k] = hv;
            W2L[(size_t)c * d2 + k] = (_Float16)rv;
        }
    }
}

// ---------------- gram fp32 (DIN=3 only): triangular tile grid, mirror write ---------
template <int DIN>
__global__ __launch_bounds__(256) void gram_kernel(const float* __restrict__ X,
                                                   const float* __restrict__ SQ,
                                                   float* __restrict__ DT) {
    __shared__ float As[32][132];
    __shared__ float Bs[32][132];
    const int t = threadIdx.x;
    const int tx = t & 15, ty = t >> 4;
    int bid = blockIdx.x;
    int bi = 0;
    while (bid >= 16 - bi) { bid -= 16 - bi; ++bi; }
    const int bj = bi + bid;
    const int i0 = bi * 128;
    const int j0 = bj * 128;
    const int z = blockIdx.z;
    const float* Xb = X + (size_t)z * NPTS * DIN;
    const float* SQb = SQ + (size_t)z * NPTS;
    float* DTb = DT + (size_t)z * NPTS * NPTS;

    const int e = t & 127;

    float acc[8][8];
    #pragma unroll
    for (int i = 0; i < 8; ++i)
        #pragma unroll
        for (int j = 0; j < 8; ++j) acc[i][j] = 0.f;

    {
        const int rh = (t >> 7) * 8;
        #pragma unroll
        for (int i = 0; i < 8; ++i) {
            int k = rh + i;
            As[rh + i][e] = (k < DIN) ? Xb[(size_t)(i0 + e) * DIN + k] : 0.f;
            Bs[rh + i][e] = (k < DIN) ? Xb[(size_t)(j0 + e) * DIN + k] : 0.f;
        }
        __syncthreads();
        #pragma unroll
        for (int r = 0; r < 16; ++r) {
            float4 a0 = *(const float4*)&As[r][ty * 4];
            float4 a1 = *(const float4*)&As[r][64 + ty * 4];
            float4 b0 = *(const float4*)&Bs[r][tx * 4];
            float4 b1 = *(const float4*)&Bs[r][64 + tx * 4];
            float av[8] = {a0.x, a0.y, a0.z, a0.w, a1.x, a1.y, a1.z, a1.w};
            float bv[8] = {b0.x, b0.y, b0.z, b0.w, b1.x, b1.y, b1.z, b1.w};
            #pragma unroll
            for (int i = 0; i < 8; ++i)
                #pragma unroll
                for (int j = 0; j < 8; ++j)
                    acc[i][j] = fmaf(av[i], bv[j], acc[i][j]);
        }
        __syncthreads();
    }

    float sqi[8], sqj[8];
    #pragma unroll
    for (int i = 0; i < 8; ++i) {
        int ro = (i < 4) ? (ty * 4 + i) : (64 + ty * 4 + (i - 4));
        sqi[i] = SQb[i0 + ro];
    }
    #pragma unroll
    for (int j = 0; j < 8; ++j) {
        int co = (j < 4) ? (tx * 4 + j) : (64 + tx * 4 + (j - 4));
        sqj[j] = SQb[j0 + co];
    }
    #pragma unroll
    for (int i = 0; i < 8; ++i) {
        int ro = (i < 4) ? (ty * 4 + i) : (64 + ty * 4 + (i - 4));
        float* out = DTb + (size_t)(i0 + ro) * NPTS + j0;
        float4 o0, o1;
        o0.x = (sqi[i] + sqj[0]) - 2.f * acc[i][0];
        o0.y = (sqi[i] + sqj[1]) - 2.f * acc[i][1];
        o0.z = (sqi[i] + sqj[2]) - 2.f * acc[i][2];
        o0.w = (sqi[i] + sqj[3]) - 2.f * acc[i][3];
        o1.x = (sqi[i] + sqj[4]) - 2.f * acc[i][4];
        o1.y = (sqi[i] + sqj[5]) - 2.f * acc[i][5];
        o1.z = (sqi[i] + sqj[6]) - 2.f * acc[i][6];
        o1.w = (sqi[i] + sqj[7]) - 2.f * acc[i][7];
        *(float4*)(out + tx * 4) = o0;
        *(float4*)(out + 64 + tx * 4) = o1;
    }
    if (bi != bj) {
        #pragma unroll
        for (int j = 0; j < 8; ++j) {
            int co = (j < 4) ? (tx * 4 + j) : (64 + tx * 4 + (j - 4));
            float* out = DTb + (size_t)(j0 + co) * NPTS + i0;
            float4 o0, o1;
            o0.x = (sqi[0] + sqj[j]) - 2.f * acc[0][j];
            o0.y = (sqi[1] + sqj[j]) - 2.f * acc[1][j];
            o0.z = (sqi[2] + sqj[j]) - 2.f * acc[2][j];
            o0.w = (sqi[3] + sqj[j]) - 2.f * acc[3][j];
            o1.x = (sqi[4] + sqj[j]) - 2.f * acc[4][j];
            o1.y = (sqi[5] + sqj[j]) - 2.f * acc[5][j];
            o1.z = (sqi[6] + sqj[j]) - 2.f * acc[6][j];
            o1.w = (sqi[7] + sqj[j]) - 2.f * acc[7][j];
            *(float4*)(out + ty * 4) = o0;
            *(float4*)(out + 64 + ty * 4) = o1;
        }
    }
}

// ======== gram MFMA (DIN%32==0): f16x3, full 16x16 tile grid, coalesced writes ======
template <int DIN>
__global__ __launch_bounds__(256) void gram_mfma_kernel(const float* __restrict__ X,
                                                        const float* __restrict__ SQ,
                                                        float* __restrict__ DT) {
    __shared__ _Float16 Ah[128][40];
    __shared__ _Float16 Al[128][40];
    __shared__ _Float16 Bh[128][40];
    __shared__ _Float16 Bl[128][40];
    const int t = threadIdx.x;
    const int bi = blockIdx.x >> 4, bj = blockIdx.x & 15;
    const int i0 = bi * 128, j0 = bj * 128;
    const int z = blockIdx.z;
    const float* Xb = X + (size_t)z * NPTS * DIN;
    const float* SQb = SQ + (size_t)z * NPTS;
    float* DTb = DT + (size_t)z * NPTS * NPTS;

    const int e = t & 127;
    const int rh = (t >> 7) * 16;   // k-half 0 or 16
    const float* Ar = Xb + (size_t)(i0 + e) * DIN + rh;
    const float* Br = Xb + (size_t)(j0 + e) * DIN + rh;

    const int w = t >> 6;
    const int lane = t & 63;
    const int wr = (w >> 1) * 64;
    const int wc = (w & 1) * 64;
    const int lr = lane & 31;
    const int lk = (lane >> 5) * 8;
    const int hsel = lane >> 5;

    floatx16 acc[2][2];
    #pragma unroll
    for (int i = 0; i < 2; ++i)
        #pragma unroll
        for (int j = 0; j < 2; ++j)
            #pragma unroll
            for (int r = 0; r < 16; ++r) acc[i][j][r] = 0.f;

    for (int k0 = 0; k0 < DIN; k0 += 32) {
        #pragma unroll
        for (int h = 0; h < 4; ++h) {
            float4 a = *(const float4*)(Ar + k0 + h * 4);
            float4 b = *(const float4*)(Br + k0 + h * 4);
            _Float16 ah0 = (_Float16)a.x, ah1 = (_Float16)a.y, ah2 = (_Float16)a.z, ah3 = (_Float16)a.w;
            half4 av, alv;
            av.x = ah0; av.y = ah1; av.z = ah2; av.w = ah3;
            alv.x = (_Float16)(a.x - (float)ah0);
            alv.y = (_Float16)(a.y - (float)ah1);
            alv.z = (_Float16)(a.z - (float)ah2);
            alv.w = (_Float16)(a.w - (float)ah3);
            *(half4*)&Ah[e][rh + h * 4] = av;
            *(half4*)&Al[e][rh + h * 4] = alv;
            _Float16 bh0 = (_Float16)b.x, bh1 = (_Float16)b.y, bh2 = (_Float16)b.z, bh3 = (_Float16)b.w;
            half4 bv, blv;
            bv.x = bh0; bv.y = bh1; bv.z = bh2; bv.w = bh3;
            blv.x = (_Float16)(b.x - (float)bh0);
            blv.y = (_Float16)(b.y - (float)bh1);
            blv.z = (_Float16)(b.z - (float)bh2);
            blv.w = (_Float16)(b.w - (float)bh3);
            *(half4*)&Bh[e][rh + h * 4] = bv;
            *(half4*)&Bl[e][rh + h * 4] = blv;
        }
        __syncthreads();
        #pragma unroll
        for (int ks = 0; ks < 2; ++ks) {
            const int kb = ks * 16 + lk;
            half8 bf0  = *(const half8*)&Bh[wc + lr][kb];
            half8 blf0 = *(const half8*)&Bl[wc + lr][kb];
            half8 bf1  = *(const half8*)&Bh[wc + 32 + lr][kb];
            half8 blf1 = *(const half8*)&Bl[wc + 32 + lr][kb];
            #pragma unroll
            for (int i = 0; i < 2; ++i) {
                half8 af  = *(const half8*)&Ah[wr + i * 32 + lr][kb];
                half8 alf = *(const half8*)&Al[wr + i * 32 + lr][kb];
                acc[i][0] = __builtin_amdgcn_mfma_f32_32x32x16_f16(af,  bf0,  acc[i][0], 0, 0, 0);
                acc[i][0] = __builtin_amdgcn_mfma_f32_32x32x16_f16(af,  blf0, acc[i][0], 0, 0, 0);
                acc[i][0] = __builtin_amdgcn_mfma_f32_32x32x16_f16(alf, bf0,  acc[i][0], 0, 0, 0);
                acc[i][1] = __builtin_amdgcn_mfma_f32_32x32x16_f16(af,  bf1,  acc[i][1], 0, 0, 0);
                acc[i][1] = __builtin_amdgcn_mfma_f32_32x32x16_f16(af,  blf1, acc[i][1], 0, 0, 0);
                acc[i][1] = __builtin_amdgcn_mfma_f32_32x32x16_f16(alf, bf1,  acc[i][1], 0, 0, 0);
            }
        }
        __syncthreads();
    }

    const float sqj0 = SQb[j0 + wc + lr];
    const float sqj1 = SQb[j0 + wc + 32 + lr];
    #pragma unroll
    for (int i = 0; i < 2; ++i) {
        #pragma unroll
        for (int r = 0; r < 16; ++r) {
            const int row = wr + i * 32 + (r & 3) + 8 * (r >> 2) + 4 * hsel;
            const float sqi = SQb[i0 + row];
            float* out = DTb + (size_t)(i0 + row) * NPTS + j0 + wc;
            out[lr]      = (sqi + sqj0) - 2.f * acc[i][0][r];
            out[32 + lr] = (sqi + sqj1) - 2.f * acc[i][1][r];
        }
    }
}

// ---------------- knn select: one query per wave, dists in registers ----------------
__global__ __launch_bounds__(256) void knn_select_kernel(const float* __restrict__ DT,
                                                         int* __restrict__ IDX, int qoff) {
    const int t = threadIdx.x;
    const int w = t >> 6, lane = t & 63;
    const int q = blockIdx.x * 4 + w;
    const float* dq = DT + (size_t)q * NPTS;
    const int l4 = lane << 2;

    float vals[32];
    #pragma unroll
    for (int s = 0; s < 8; ++s) {
        float4 v = *(const float4*)(dq + s * 256 + l4);
        vals[s * 4 + 0] = v.x; vals[s * 4 + 1] = v.y;
        vals[s * 4 + 2] = v.z; vals[s * 4 + 3] = v.w;
    }
    unsigned rm = 0;
    float best = INFINITY; int bslot = 32;
    #pragma unroll
    for (int sl = 0; sl < 32; ++sl)
        if (vals[sl] < best) { best = vals[sl]; bslot = sl; }

    for (int rep = 0; rep < KNN; ++rep) {
        int bj = (bslot < 32) ? ((bslot >> 2) * 256 + l4 + (bslot & 3)) : NPTS;
        float gb = best; int gj = bj;
        #pragma unroll
        for (int off = 1; off < 64; off <<= 1) {
            float ov = __shfl_xor(gb, off);
            int oj = __shfl_xor(gj, off);
            if (ov < gb || (ov == gb && oj < gj)) { gb = ov; gj = oj; }
        }
        if (lane == 0) IDX[(size_t)(qoff + q) * KNN + rep] = gj;
        if (((gj >> 2) & 63) == lane) {
            int slot = ((gj >> 8) << 2) | (gj & 3);
            rm |= (1u << slot);
            best = INFINITY; bslot = 32;
            #pragma unroll
            for (int sl = 0; sl < 32; ++sl)
                if (!(rm & (1u << sl)) && vals[sl] < best) { best = vals[sl]; bslot = sl; }
        }
    }
}

// ---------------- gemm big: C[M,N] = A[M,K]@B[K,N] + bias, 128x128, BK=32, plain -----
template <int KK, int NN>
__global__ __launch_bounds__(256) void gemm_big_kernel(const float* __restrict__ A,
                                                       const float* __restrict__ B,
                                                       const float* __restrict__ bias,
                                                       float* __restrict__ C) {
    __shared__ float As[32][132];
    __shared__ float Bs[32][132];
    const int t = threadIdx.x;
    const int tx = t & 15, ty = t >> 4;
    const int m0 = blockIdx.x * 128;
    const int c0 = blockIdx.y * 128;

    float acc[8][8];
    #pragma unroll
    for (int i = 0; i < 8; ++i)
        #pragma unroll
        for (int j = 0; j < 8; ++j) acc[i][j] = 0.f;

    const int e = t & 127;
    const int rh = (t >> 7) * 16;
    const float* Ar = A + (size_t)(m0 + e) * KK + rh;
    const int br = t & 31;
    const int bc = (t >> 5) * 16;
    const float* Wbase = B + (size_t)br * NN + c0 + bc;

    for (int k0 = 0; k0 < KK; k0 += 32) {
        #pragma unroll
        for (int h = 0; h < 4; ++h) {
            float4 a = *(const float4*)(Ar + k0 + h * 4);
            As[rh + h * 4 + 0][e] = a.x; As[rh + h * 4 + 1][e] = a.y;
            As[rh + h * 4 + 2][e] = a.z; As[rh + h * 4 + 3][e] = a.w;
            *(float4*)&Bs[br][bc + h * 4] = *(const float4*)(Wbase + (size_t)k0 * NN + h * 4);
        }
        __syncthreads();
        #pragma unroll
        for (int r = 0; r < 32; ++r) {
            float4 a0 = *(const float4*)&As[r][ty * 4];
            float4 a1 = *(const float4*)&As[r][64 + ty * 4];
            float4 b0 = *(const float4*)&Bs[r][tx * 4];
            float4 b1 = *(const float4*)&Bs[r][64 + tx * 4];
            float av[8] = {a0.x, a0.y, a0.z, a0.w, a1.x, a1.y, a1.z, a1.w};
            float bv[8] = {b0.x, b0.y, b0.z, b0.w, b1.x, b1.y, b1.z, b1.w};
            #pragma unroll
            for (int i = 0; i < 8; ++i)
                #pragma unroll
                for (int j = 0; j < 8; ++j)
                    acc[i][j] = fmaf(av[i], bv[j], acc[i][j]);
        }
        __syncthreads();
    }

    float bvv[8];
    #pragma unroll
    for (int j = 0; j < 8; ++j) {
        int co = (j < 4) ? (tx * 4 + j) : (64 + tx * 4 + (j - 4));
        bvv[j] = bias[c0 + co];
    }
    #pragma unroll
    for (int i = 0; i < 8; ++i) {
        int ro = (i < 4) ? (ty * 4 + i) : (64 + ty * 4 + (i - 4));
        float* out = C + (size_t)(m0 + ro) * NN + c0;
        float4 o0, o1;
        o0.x = acc[i][0] + bvv[0]; o0.y = acc[i][1] + bvv[1];
        o0.z = acc[i][2] + bvv[2]; o0.w = acc[i][3] + bvv[3];
        o1.x = acc[i][4] + bvv[4]; o1.y = acc[i][5] + bvv[5];
        o1.z = acc[i][6] + bvv[6]; o1.w = acc[i][7] + bvv[7];
        *(float4*)(out + tx * 4) = o0;
        *(float4*)(out + 64 + tx * 4) = o1;
    }
}

// ---------------- generic tiled GEMM (fallback, 64x64): C = A@B + bias ----------------
template <int KK, int NN>
__global__ __launch_bounds__(256) void gemm_pq_kernel(const float* __restrict__ A,
                                                      const float* __restrict__ B,
                                                      const float* __restrict__ bias,
                                                      float* __restrict__ C) {
    __shared__ float As[16][68];
    __shared__ float Bs[16][64];
    const int t = threadIdx.x;
    const int tx = t & 15, ty = t >> 4;
    const int m0 = blockIdx.x * 64;
    const int c0 = blockIdx.y * 64;
    float acc[4][4];
    #pragma unroll
    for (int i = 0; i < 4; ++i)
        #pragma unroll
        for (int j = 0; j < 4; ++j) acc[i][j] = 0.f;

    constexpr int KCH = (KK + 15) / 16;
    for (int kc = 0; kc < KCH; ++kc) {
        const int k0 = kc * 16;
        {
            int m = t & 63;
            int r4 = (t >> 6) * 4;
            if constexpr (KK % 16 == 0) {
                float4 v = *(const float4*)(A + (size_t)(m0 + m) * KK + k0 + r4);
                As[r4 + 0][m] = v.x; As[r4 + 1][m] = v.y;
                As[r4 + 2][m] = v.z; As[r4 + 3][m] = v.w;
            } else {
                #pragma unroll
                for (int i = 0; i < 4; ++i) {
                    int r = r4 + i;
                    As[r][m] = (k0 + r < KK) ? A[(size_t)(m0 + m) * KK + k0 + r] : 0.f;
                }
            }
        }
        {
            int r = t >> 4;
            int c = (t & 15) * 4;
            float4 v = make_float4(0.f, 0.f, 0.f, 0.f);
            if (k0 + r < KK) v = *(const float4*)(B + (size_t)(k0 + r) * NN + c0 + c);
            *(float4*)&Bs[r][c] = v;
        }
        __syncthreads();
        #pragma unroll
        for (int r = 0; r < 16; ++r) {
            float4 a4 = *(const float4*)&As[r][ty * 4];
            float4 b4 = *(const float4*)&Bs[r][tx * 4];
            float av[4] = {a4.x, a4.y, a4.z, a4.w};
            float bv[4] = {b4.x, b4.y, b4.z, b4.w};
            #pragma unroll
            for (int i = 0; i < 4; ++i)
                #pragma unroll
                for (int j = 0; j < 4; ++j)
                    acc[i][j] = fmaf(av[i], bv[j], acc[i][j]);
        }
        __syncthreads();
    }
    float4 bv4 = *(const float4*)(bias + c0 + tx * 4);
    float bv[4] = {bv4.x, bv4.y, bv4.z, bv4.w};
    #pragma unroll
    for (int i = 0; i < 4; ++i) {
        float4 o;
        o.x = acc[i][0] + bv[0];
        o.y = acc[i][1] + bv[1];
        o.z = acc[i][2] + bv[2];
        o.w = acc[i][3] + bv[3];
        *(float4*)(C + (size_t)(m0 + ty * 4 + i) * NN + c0 + tx * 4) = o;
    }
}

// ---------------- edge small (DOUT<=32): 64 edges x 64 cols, 4x4/thread ----------
template <int D2, int DOUT>
__global__ __launch_bounds__(256) void edge_kernel(const float* __restrict__ PQ,
                                                   const int* __restrict__ IDX,
                                                   const float* __restrict__ W2,
                                                   const float* __restrict__ b2,
                                                   float* __restrict__ Xn) {
    constexpr int N4 = 2 * D2;
    __shared__ float As[16][68];
    __shared__ float Bs[16][64];
    __shared__ int gjs[64];
    const int t = threadIdx.x;
    const int tx = t & 15, ty = t >> 4;
    const int nb = blockIdx.x * 4;
    const int c0 = blockIdx.y * 64;

    if (t < 64) {
        int node = nb + (t >> 4);
        int bstart = (node / NPTS) * NPTS;
        gjs[t] = bstart + IDX[(size_t)node * KNN + (t & 15)];
    }
    __syncthreads();

    float acc[4][4];
    #pragma unroll
    for (int i = 0; i < 4; ++i)
        #pragma unroll
        for (int j = 0; j < 4; ++j) acc[i][j] = 0.f;

    const int e = t & 63;
    const int r4 = (t >> 6) * 4;
    const int gi = nb + (e >> 4);

    for (int k0 = 0; k0 < D2; k0 += 16) {
        {
            int gj = gjs[e];
            float4 p = *(const float4*)(PQ + (size_t)gi * N4 + k0 + r4);
            float4 q = *(const float4*)(PQ + (size_t)gj * N4 + D2 + k0 + r4);
            As[r4 + 0][e] = fmaxf(p.x + q.x, 0.f);
            As[r4 + 1][e] = fmaxf(p.y + q.y, 0.f);
            As[r4 + 2][e] = fmaxf(p.z + q.z, 0.f);
            As[r4 + 3][e] = fmaxf(p.w + q.w, 0.f);
        }
        {
            int r = t >> 4;
            int c = (t & 15) * 4;
            float4 v = make_float4(0.f, 0.f, 0.f, 0.f);
            if (c0 + c < DOUT) v = *(const float4*)(W2 + (size_t)(k0 + r) * DOUT + c0 + c);
            *(float4*)&Bs[r][c] = v;
        }
        __syncthreads();
        #pragma unroll
        for (int r = 0; r < 16; ++r) {
            float4 a4 = *(const float4*)&As[r][ty * 4];
            float4 b4 = *(const float4*)&Bs[r][tx * 4];
            float av[4] = {a4.x, a4.y, a4.z, a4.w};
            float bv[4] = {b4.x, b4.y, b4.z, b4.w};
            #pragma unroll
            for (int i = 0; i < 4; ++i)
                #pragma unroll
                for (int j = 0; j < 4; ++j)
                    acc[i][j] = fmaf(av[i], bv[j], acc[i][j]);
        }
        __syncthreads();
    }

    float bv[4];
    #pragma unroll
    for (int j = 0; j < 4; ++j) {
        int c = c0 + tx * 4 + j;
        bv[j] = (c < DOUT) ? b2[c] : 0.f;
    }
    float s[4];
    #pragma unroll
    for (int j = 0; j < 4; ++j) {
        float ss = 0.f;
        #pragma unroll
        for (int i = 0; i < 4; ++i) ss += fmaxf(acc[i][j] + bv[j], 0.f);
        s[j] = ss;
    }
    #pragma unroll
    for (int j = 0; j < 4; ++j) Bs[ty][tx * 4 + j] = s[j];
    __syncthreads();
    if ((ty & 3) == 0) {
        int node = nb + (ty >> 2);
        #pragma unroll
        for (int j = 0; j < 4; ++j) {
            int c = c0 + tx * 4 + j;
            if (c < DOUT) {
                int cc = tx * 4 + j;
                float tot = Bs[ty][cc] + Bs[ty + 1][cc] + Bs[ty + 2][cc] + Bs[ty + 3][cc];
                Xn[(size_t)node * DOUT + c] = tot * (1.f / 16.f);
            }
        }
    }
}

// ======== edge big (DOUT>=128): f16x3 MFMA, 128x128 tile, A-LDS dbuf (41.5 KB ->
// 3 blocks/CU), B in persistent regs (refilled after last use, ~1-iter flight),
// single barrier per K-step. Combines round-7's schedule with round-4's occupancy;
// 3 independent barrier groups per SIMD hide dependency stalls. Bit-exact vs r4-r8.
struct BRegs { half8 h0, l0, h1, l1, h2, l2, h3, l3; };

#define EBG_LOAD_A(KN)                                                               \
  { _Pragma("unroll")                                                                \
    for (int h = 0; h < 4; ++h) {                                                    \
      pp[h] = *(const float4*)(Prow + (KN) + rh + h * 4);                            \
      qq[h] = *(const float4*)(Qrow + (KN) + rh + h * 4);                            \
    } }

#define EBG_LOAD_B(KN)                                                               \
  { bb.h0 = *(const half8*)(WH0 + (KN) + lk);                                        \
    bb.l0 = *(const half8*)(WL0 + (KN) + lk);                                        \
    bb.h1 = *(const half8*)(WH1 + (KN) + lk);                                        \
    bb.l1 = *(const half8*)(WL1 + (KN) + lk);                                        \
    bb.h2 = *(const half8*)(WH0 + (KN) + 16 + lk);                                   \
    bb.l2 = *(const half8*)(WL0 + (KN) + 16 + lk);                                   \
    bb.h3 = *(const half8*)(WH1 + (KN) + 16 + lk);                                   \
    bb.l3 = *(const half8*)(WL1 + (KN) + 16 + lk); }

#define EBG_STAGE(dst)                                                               \
  { _Pragma("unroll")                                                                \
    for (int h = 0; h < 4; ++h) {                                                    \
      float a0 = fmaxf(pp[h].x + qq[h].x, 0.f);                                      \
      float a1 = fmaxf(pp[h].y + qq[h].y, 0.f);                                      \
      float a2 = fmaxf(pp[h].z + qq[h].z, 0.f);                                      \
      float a3 = fmaxf(pp[h].w + qq[h].w, 0.f);                                      \
      _Float16 h0 = (_Float16)a0, h1 = (_Float16)a1;                                 \
      _Float16 h2 = (_Float16)a2, h3 = (_Float16)a3;                                 \
      half4 hv, lv;                                                                  \
      hv.x = h0; hv.y = h1; hv.z = h2; hv.w = h3;                                    \
      lv.x = (_Float16)(a0 - (float)h0);                                             \
      lv.y = (_Float16)(a1 - (float)h1);                                             \
      lv.z = (_Float16)(a2 - (float)h2);                                             \
      lv.w = (_Float16)(a3 - (float)h3);                                             \
      *(half4*)&Ah[dst][e][rh + h * 4] = hv;                                         \
      *(half4*)&Al[dst][e][rh + h * 4] = lv;                                         \
    } }

#define EBG_MFMA(cur)                                                                \
  { _Pragma("unroll")                                                                \
    for (int i = 0; i < 2; ++i) {   /* ks = 0 */                                     \
      half8 af  = *(const half8*)&Ah[cur][wr + i * 32 + lr][lk];                     \
      half8 alf = *(const half8*)&Al[cur][wr + i * 32 + lr][lk];                     \
      acc[i][0] = __builtin_amdgcn_mfma_f32_32x32x16_f16(af,  bb.h0, acc[i][0], 0, 0, 0);  \
      acc[i][0] = __builtin_amdgcn_mfma_f32_32x32x16_f16(af,  bb.l0, acc[i][0], 0, 0, 0);  \
      acc[i][0] = __builtin_amdgcn_mfma_f32_32x32x16_f16(alf, bb.h0, acc[i][0], 0, 0, 0);  \
      acc[i][1] = __builtin_amdgcn_mfma_f32_32x32x16_f16(af,  bb.h1, acc[i][1], 0, 0, 0);  \
      acc[i][1] = __builtin_amdgcn_mfma_f32_32x32x16_f16(af,  bb.l1, acc[i][1], 0, 0, 0);  \
      acc[i][1] = __builtin_amdgcn_mfma_f32_32x32x16_f16(alf, bb.h1, acc[i][1], 0, 0, 0);  \
    }                                                                                \
    _Pragma("unroll")                                                                \
    for (int i = 0; i < 2; ++i) {   /* ks = 1 */                                     \
      half8 af  = *(const half8*)&Ah[cur][wr + i * 32 + lr][16 + lk];                \
      half8 alf = *(const half8*)&Al[cur][wr + i * 32 + lr][16 + lk];                \
      acc[i][0] = __builtin_amdgcn_mfma_f32_32x32x16_f16(af,  bb.h2, acc[i][0], 0, 0, 0);  \
      acc[i][0] = __builtin_amdgcn_mfma_f32_32x32x16_f16(af,  bb.l2, acc[i][0], 0, 0, 0);  \
      acc[i][0] = __builtin_amdgcn_mfma_f32_32x32x16_f16(alf, bb.h2, acc[i][0], 0, 0, 0);  \
      acc[i][1] = __builtin_amdgcn_mfma_f32_32x32x16_f16(af,  bb.h3, acc[i][1], 0, 0, 0);  \
      acc[i][1] = __builtin_amdgcn_mfma_f32_32x32x16_f16(af,  bb.l3, acc[i][1], 0, 0, 0);  \
      acc[i][1] = __builtin_amdgcn_mfma_f32_32x32x16_f16(alf, bb.h3, acc[i][1], 0, 0, 0);  \
    } }

template <int D2, int DOUT>
__global__ __launch_bounds__(256) void edge_big_mfma_kernel(const float* __restrict__ PQ,
                                                            const int* __restrict__ IDX,
                                                            const _Float16* __restrict__ W2H,
                                                            const _Float16* __restrict__ W2L,
                                                            const float* __restrict__ b2,
                                                            float* __restrict__ Xn) {
    constexpr int N4 = 2 * D2;
    constexpr int NSTEP = D2 / 32;
    __shared__ _Float16 Ah[2][128][40];
    __shared__ _Float16 Al[2][128][40];
    __shared__ int gjs[128];
    const int t = threadIdx.x;
    const int nb8 = blockIdx.x * 8;
    const int c0 = blockIdx.y * 128;

    if (t < 128) {
        int node = nb8 + (t >> 4);
        int bstart = (node / NPTS) * NPTS;
        gjs[t] = bstart + IDX[(size_t)node * KNN + (t & 15)];
    }
    __syncthreads();

    const int e = t & 127;          // A row (edge)
    const int rh = (t >> 7) * 16;   // k half: 0 or 16
    const int gi = nb8 + (e >> 4);
    const int gj = gjs[e];
    const float* Prow = PQ + (size_t)gi * N4;
    const float* Qrow = PQ + (size_t)gj * N4 + D2;

    const int w = t >> 6;
    const int lane = t & 63;
    const int wr = (w >> 1) * 64;
    const int wc = (w & 1) * 64;
    const int lr = lane & 31;
    const int lk = (lane >> 5) * 8;
    const int hsel = lane >> 5;

    const _Float16* WH0 = W2H + (size_t)(c0 + wc + lr) * D2;
    const _Float16* WH1 = WH0 + (size_t)32 * D2;
    const _Float16* WL0 = W2L + (size_t)(c0 + wc + lr) * D2;
    const _Float16* WL1 = WL0 + (size_t)32 * D2;

    floatx16 acc[2][2];
    #pragma unroll
    for (int i = 0; i < 2; ++i)
        #pragma unroll
        for (int j = 0; j < 2; ++j)
            #pragma unroll
            for (int r = 0; r < 16; ++r) acc[i][j][r] = 0.f;

    float4 pp[4], qq[4];
    BRegs bb;

    // prologue: stage tile 0; preload tile-1 A regs; B regs hold tile 0
    EBG_LOAD_A(0)
    EBG_LOAD_B(0)
    EBG_STAGE(0)
    EBG_LOAD_A(32)
    asm volatile("s_waitcnt lgkmcnt(0)" ::: "memory");
    __builtin_amdgcn_s_barrier();
    asm volatile("" ::: "memory");

    for (int s = 0; s < NSTEP - 1; ++s) {
        const int cur = s & 1;
        EBG_MFMA(cur)                 // tile s, B from bb
        EBG_STAGE(cur ^ 1)            // tile s+1 from resident pp/qq
        EBG_LOAD_B(32 * (s + 1))      // bb <- tile s+1 (consumed next iter; ~1-iter flight)
        if (s + 2 < NSTEP) EBG_LOAD_A(32 * (s + 2))   // pp/qq <- tile s+2
        asm volatile("s_waitcnt lgkmcnt(0)" ::: "memory");
        __builtin_amdgcn_s_barrier();
        asm volatile("" ::: "memory");
    }
    EBG_MFMA((NSTEP - 1) & 1)

    // --- epilogue: relu(+bias), mean over 16 neighbor-rows, write node outputs ---
    float bbias[2];
    bbias[0] = b2[c0 + wc + lr];
    bbias[1] = b2[c0 + wc + 32 + lr];
    #pragma unroll
    for (int i = 0; i < 2; ++i) {
        int node0 = nb8 + ((wr + i * 32) >> 4);
        #pragma unroll
        for (int j = 0; j < 2; ++j) {
            float sA = 0.f, sB = 0.f;
            #pragma unroll
            for (int r = 0; r < 8; ++r)  sA += fmaxf(acc[i][j][r] + bbias[j], 0.f);
            #pragma unroll
            for (int r = 8; r < 16; ++r) sB += fmaxf(acc[i][j][r] + bbias[j], 0.f);
            sA += __shfl_xor(sA, 32);
            sB += __shfl_xor(sB, 32);
            if (hsel == 0) {
                int col = c0 + wc + j * 32 + lr;
                Xn[(size_t)node0 * DOUT + col] = sA * (1.f / 16.f);
                Xn[(size_t)(node0 + 1) * DOUT + col] = sB * (1.f / 16.f);
            }
        }
    }
}
#undef EBG_LOAD_A
#undef EBG_LOAD_B
#undef EBG_STAGE
#undef EBG_MFMA

// ======== edge mid (DOUT==64): f16x3 MFMA, round-4 depth-2 pipeline, 64x32/wave =====
#define EM_STAGE_MFMA(KC, QQ, POK, KP)                                               \
  {                                                                                  \
    half8 wh0 = *(const half8*)(WHrow + (KC));                                       \
    half8 wl0 = *(const half8*)(WLrow + (KC));                                       \
    _Pragma("unroll")                                                                \
    for (int h = 0; h < 4; ++h) {                                                    \
      float4 p = *(const float4*)(Prow + (KC) + rh + h * 4);                         \
      float a0 = fmaxf(p.x + QQ[h].x, 0.f);                                          \
      float a1 = fmaxf(p.y + QQ[h].y, 0.f);                                          \
      float a2 = fmaxf(p.z + QQ[h].z, 0.f);                                          \
      float a3 = fmaxf(p.w + QQ[h].w, 0.f);                                          \
      _Float16 h0 = (_Float16)a0, h1 = (_Float16)a1;                                 \
      _Float16 h2 = (_Float16)a2, h3 = (_Float16)a3;                                 \
      half4 hv, lv;                                                                  \
      hv.x = h0; hv.y = h1; hv.z = h2; hv.w = h3;                                    \
      lv.x = (_Float16)(a0 - (float)h0);                                             \
      lv.y = (_Float16)(a1 - (float)h1);                                             \
      lv.z = (_Float16)(a2 - (float)h2);                                             \
      lv.w = (_Float16)(a3 - (float)h3);                                             \
      *(half4*)&Ah[e][rh + h * 4] = hv;                                              \
      *(half4*)&Al[e][rh + h * 4] = lv;                                              \
    }                                                                                \
    *(half8*)&Bh[wrB][wkB] = wh0;                                                    \
    *(half8*)&Bl[wrB][wkB] = wl0;                                                    \
    if (POK) {                                                                       \
      _Pragma("unroll")                                                              \
      for (int h = 0; h < 4; ++h)                                                    \
        QQ[h] = *(const float4*)(Qrow + (KP) + rh + h * 4);                          \
    }                                                                                \
    asm volatile("s_waitcnt lgkmcnt(0)" ::: "memory");                               \
    __builtin_amdgcn_s_barrier();                                                    \
    asm volatile("" ::: "memory");                                                   \
    _Pragma("unroll")                                                                \
    for (int ks = 0; ks < 2; ++ks) {                                                 \
      const int kb = ks * 16 + lk;                                                   \
      half8 bf0 = *(const half8*)&Bh[wc + lr][kb];                                   \
      half8 blf0 = *(const half8*)&Bl[wc + lr][kb];                                  \
      _Pragma("unroll")                                                              \
      for (int i = 0; i < 2; ++i) {                                                  \
        half8 af = *(const half8*)&Ah[wr + i * 32 + lr][kb];                         \
        half8 alf = *(const half8*)&Al[wr + i * 32 + lr][kb];                        \
        acc[i] = __builtin_amdgcn_mfma_f32_32x32x16_f16(af, bf0, acc[i], 0, 0, 0);   \
        acc[i] = __builtin_amdgcn_mfma_f32_32x32x16_f16(af, blf0, acc[i], 0, 0, 0);  \
        acc[i] = __builtin_amdgcn_mfma_f32_32x32x16_f16(alf, bf0, acc[i], 0, 0, 0);  \
      }                                                                              \
    }                                                                                \
    asm volatile("" ::: "memory");                                                   \
    __builtin_amdgcn_s_barrier();                                                    \
    asm volatile("" ::: "memory");                                                   \
  }

template <int D2, int DOUT>
__global__ __launch_bounds__(256) void edge_mid_mfma_kernel(const float* __restrict__ PQ,
                                                            const int* __restrict__ IDX,
                                                            const _Float16* __restrict__ W2H,
                                                            const _Float16* __restrict__ W2L,
                                                            const float* __restrict__ b2,
                                                            float* __restrict__ Xn) {
    constexpr int N4 = 2 * D2;
    __shared__ _Float16 Ah[128][40];
    __shared__ _Float16 Al[128][40];
    __shared__ _Float16 Bh[64][40];
    __shared__ _Float16 Bl[64][40];
    __shared__ int gjs[128];
    const int t = threadIdx.x;
    const int nb8 = blockIdx.x * 8;

    if (t < 128) {
        int node = nb8 + (t >> 4);
        int bstart = (node / NPTS) * NPTS;
        gjs[t] = bstart + IDX[(size_t)node * KNN + (t & 15)];
    }
    __syncthreads();

    const int e = t & 127;
    const int rh = (t >> 7) * 16;
    const int gi = nb8 + (e >> 4);
    const int gj = gjs[e];
    const float* Prow = PQ + (size_t)gi * N4;
    const float* Qrow = PQ + (size_t)gj * N4 + D2;
    const int wrB = t & 63;
    const int wkB = (t >> 6) * 8;
    const _Float16* WHrow = W2H + (size_t)wrB * D2 + wkB;
    const _Float16* WLrow = W2L + (size_t)wrB * D2 + wkB;

    const int w = t >> 6;
    const int lane = t & 63;
    const int wr = (w >> 1) * 64;
    const int wc = (w & 1) * 32;
    const int lr = lane & 31;
    const int lk = (lane >> 5) * 8;
    const int hsel = lane >> 5;

    floatx16 acc[2];
    #pragma unroll
    for (int i = 0; i < 2; ++i)
        #pragma unroll
        for (int r = 0; r < 16; ++r) acc[i][r] = 0.f;

    float4 qqA[4], qqB[4];
    #pragma unroll
    for (int h = 0; h < 4; ++h) qqA[h] = *(const float4*)(Qrow + rh + h * 4);
    #pragma unroll
    for (int h = 0; h < 4; ++h) qqB[h] = *(const float4*)(Qrow + 32 + rh + h * 4);

    for (int k0 = 0; k0 < D2; k0 += 64) {
        EM_STAGE_MFMA(k0,      qqA, (k0 + 64 < D2), k0 + 64)
        EM_STAGE_MFMA(k0 + 32, qqB, (k0 + 96 < D2), k0 + 96)
    }

    float bb = b2[wc + lr];
    #pragma unroll
    for (int i = 0; i < 2; ++i) {
        int node0 = nb8 + ((wr + i * 32) >> 4);
        float sA = 0.f, sB = 0.f;
        #pragma unroll
        for (int r = 0; r < 8; ++r)  sA += fmaxf(acc[i][r] + bb, 0.f);
        #pragma unroll
        for (int r = 8; r < 16; ++r) sB += fmaxf(acc[i][r] + bb, 0.f);
        sA += __shfl_xor(sA, 32);
        sB += __shfl_xor(sB, 32);
        if (hsel == 0) {
            int col = wc + lr;
            Xn[(size_t)node0 * DOUT + col] = sA * (1.f / 16.f);
            Xn[(size_t)(node0 + 1) * DOUT + col] = sB * (1.f / 16.f);
        }
    }
}
#undef EM_STAGE_MFMA

// ---------------- final: mean over nodes + 16x2 projection ----------------
__global__ __launch_bounds__(256) void final_kernel(const float* __restrict__ X,
                                                    const float* __restrict__ Wf,
                                                    const float* __restrict__ bfin,
                                                    float* __restrict__ out) {
    __shared__ float red[16][17];
    __shared__ float pool[16];
    const int b = blockIdx.x;
    const int t = threadIdx.x;
    const int c = t & 15, rg = t >> 4;
    float s = 0.f;
    for (int n = rg; n < NPTS; n += 16) s += X[(size_t)(b * NPTS + n) * 16 + c];
    red[rg][c] = s;
    __syncthreads();
    if (t < 16) {
        float tot = 0.f;
        #pragma unroll
        for (int i = 0; i < 16; ++i) tot += red[i][t];
        pool[t] = tot * (1.f / NPTS);
    }
    __syncthreads();
    if (t < 2) {
        float a = bfin[t];
        #pragma unroll
        for (int cc = 0; cc < 16; ++cc) a = fmaf(pool[cc], Wf[cc * 2 + t], a);
        out[b * 2 + t] = a;
    }
}

// ---------------- per-layer driver ----------------
template <int DIN, int DOUT>
static void run_layer(const float* Xin, float* Xout, float* PQ, float* SQ, int* IDX,
                      float* WCAT, float* BCAT, _Float16* W2H, _Float16* W2L,
                      const float* W1, const float* b1, const float* W2, const float* b2,
                      hipStream_t stream) {
    constexpr int D2 = 2 * DOUT;
    constexpr int N4 = 2 * D2;
    constexpr int prep_blocks = (DIN * N4 + 255) / 256;
    constexpr int w2_blocks = (DOUT >= 64) ? ((D2 * DOUT + 255) / 256) : 0;
    sqprep_kernel<<<BN / 256 + prep_blocks + w2_blocks, 256, 0, stream>>>(
        Xin, SQ, W1, b1, WCAT, BCAT, DIN, D2, W2, W2H, W2L,
        (DOUT >= 64) ? DOUT : 0, prep_blocks);
    for (int h = 0; h < 2; ++h) {
        if constexpr (DIN % 32 == 0) {
            dim3 gg(256, 1, 4);   // full 16x16 tile grid, coalesced writes
            gram_mfma_kernel<DIN><<<gg, 256, 0, stream>>>(Xin + (size_t)h * 4 * NPTS * DIN,
                                                          SQ + (size_t)h * 4 * NPTS, PQ);
        } else {
            dim3 gg(136, 1, 4);   // triangular fp32 path (DIN=3)
            gram_kernel<DIN><<<gg, 256, 0, stream>>>(Xin + (size_t)h * 4 * NPTS * DIN,
                                                     SQ + (size_t)h * 4 * NPTS, PQ);
        }
        knn_select_kernel<<<2048, 256, 0, stream>>>(PQ, IDX, h * 8192);
    }
    if constexpr (N4 % 128 == 0 && DIN % 32 == 0) {
        dim3 g1(BN / 128, N4 / 128);
        gemm_big_kernel<DIN, N4><<<g1, 256, 0, stream>>>(Xin, WCAT, BCAT, PQ);
    } else {
        dim3 g1(BN / 64, N4 / 64);
        gemm_pq_kernel<DIN, N4><<<g1, 256, 0, stream>>>(Xin, WCAT, BCAT, PQ);
    }
    if constexpr (DOUT >= 128) {
        dim3 g2(BN / 8, DOUT / 128);
        edge_big_mfma_kernel<D2, DOUT><<<g2, 256, 0, stream>>>(PQ, IDX, W2H, W2L, b2, Xout);
    } else if constexpr (DOUT == 64) {
        dim3 g2(BN / 8, 1);
        edge_mid_mfma_kernel<D2, DOUT><<<g2, 256, 0, stream>>>(PQ, IDX, W2H, W2L, b2, Xout);
    } else {
        dim3 g2(BN / 4, (DOUT + 63) / 64);
        edge_kernel<D2, DOUT><<<g2, 256, 0, stream>>>(PQ, IDX, W2, b2, Xout);
    }
}

extern "C" void kernel_launch(void* const* d_in, const int* in_sizes, int n_in,
                              void* d_out, int out_size, void* d_ws, size_t ws_size,
                              hipStream_t stream) {
    (void)in_sizes; (void)n_in; (void)out_size; (void)ws_size;
    const float* x = (const float*)d_in[0];
    const float* W1a[6]; const float* b1a[6]; const float* W2a[6]; const float* b2a[6];
    for (int l = 0; l < 6; ++l) {
        W1a[l] = (const float*)d_in[1 + 4 * l];
        b1a[l] = (const float*)d_in[2 + 4 * l];
        W2a[l] = (const float*)d_in[3 + 4 * l];
        b2a[l] = (const float*)d_in[4 + 4 * l];
    }
    const float* Wf = (const float*)d_in[25];
    const float* bfin = (const float*)d_in[26];

    float* ws = (float*)d_ws;
    float* X0   = ws;                                   // 16384*256
    float* X1   = X0 + (size_t)BN * 256;                // 16384*256
    float* PQ   = X1 + (size_t)BN * 256;                // 16384*1024 (also knn DT)
    float* SQ   = PQ + (size_t)BN * 1024;               // 16384
    int*   IDX  = (int*)(SQ + BN);                      // 16384*16
    float* WCAT = (float*)(IDX + (size_t)BN * KNN);     // 131072
    float* BCAT = WCAT + 131072;                        // 1024
    _Float16* W2H = (_Float16*)(BCAT + 1024);           // 131072 halfs (256 KB)
    _Float16* W2L = W2H + 131072;                       // 131072 halfs (256 KB)

    run_layer<3,   32>(x,  X0, PQ, SQ, IDX, WCAT, BCAT, W2H, W2L, W1a[0], b1a[0], W2a[0], b2a[0], stream);
    run_layer<32, 128>(X0, X1, PQ, SQ, IDX, WCAT, BCAT, W2H, W2L, W1a[1], b1a[1], W2a[1], b2a[1], stream);
    run_layer<128,256>(X1, X0, PQ, SQ, IDX, WCAT, BCAT, W2H, W2L, W1a[2], b1a[2], W2a[2], b2a[2], stream);
    run_layer<256, 64>(X0, X1, PQ, SQ, IDX, WCAT, BCAT, W2H, W2L, W1a[3], b1a[3], W2a[3], b2a[3], stream);
    run_layer<64,  32>(X1, X0, PQ, SQ, IDX, WCAT, BCAT, W2H, W2L, W1a[4], b1a[4], W2a[4], b2a[4], stream);
    run_layer<32,  16>(X0, X1, PQ, SQ, IDX, WCAT, BCAT, W2H, W2L, W1a[5], b1a[5], W2a[5], b2a[5], stream);
    final_kernel<<<NB, 256, 0, stream>>>(X1, Wf, bfin, (float*)d_out);
}

// Round 10
// 1803.532 us; speedup vs baseline: 1.0309x; 1.0309x over previous
//
#include <hip/hip_runtime.h>
#include <math.h>

#define NPTS 2048
#define NB 8
#define BN 16384   // NB*NPTS
#define KNN 16

typedef _Float16 half4 __attribute__((ext_vector_type(4)));
typedef _Float16 half8 __attribute__((ext_vector_type(8)));
typedef float floatx16 __attribute__((ext_vector_type(16)));

// ---------------- fused sq + prep: sq | Wcat/bcat | W2 hi/lo split (transposed) ------
__global__ __launch_bounds__(256) void sqprep_kernel(const float* __restrict__ X,
                                                     float* __restrict__ SQ,
                                                     const float* __restrict__ W1,
                                                     const float* __restrict__ b1,
                                                     float* __restrict__ Wcat,
                                                     float* __restrict__ bcat,
                                                     int din, int d2,
                                                     const float* __restrict__ W2,
                                                     _Float16* __restrict__ W2H,
                                                     _Float16* __restrict__ W2L,
                                                     int dout, int pb) {
    const int bid = blockIdx.x;
    if (bid < BN / 256) {
        int g = bid * 256 + threadIdx.x;
        const float* row = X + (size_t)g * din;
        float s = 0.f;
        for (int d = 0; d < din; ++d) s = fmaf(row[d], row[d], s);
        SQ[g] = s;
    } else if (bid < BN / 256 + pb) {
        int n4 = 2 * d2;
        int total = din * n4;
        int i = (bid - BN / 256) * 256 + threadIdx.x;
        if (i < total) {
            int d = i / n4, c = i - d * n4;
            float v;
            if (c < d2) v = W1[d * d2 + c] - W1[(din + d) * d2 + c];
            else        v = W1[(din + d) * d2 + (c - d2)];
            Wcat[i] = v;
        }
        if (i < n4) bcat[i] = (i < d2) ? b1[i] : 0.f;
    } else {
        // W2 split: W2 is [d2][dout] fp32 -> W2H/W2L [dout][d2] f16 (hi + residual lo)
        int i = (bid - BN / 256 - pb) * 256 + threadIdx.x;
        if (i < d2 * dout) {
            int k = i / dout, c = i - k * dout;
            float wv = W2[i];
            _Float16 hv = (_Float16)wv;
            float rv = wv - (float)hv;
            W2H[(size_t)c * d2 + k] = hv;
            W2L[(size_t)c * d2 + k] = (_Float16)rv;
        }
    }
}

// ---------------- gram fp32 (DIN=3 only): triangular tile grid, mirror write ---------
template <int DIN>
__global__ __launch_bounds__(256) void gram_kernel(const float* __restrict__ X,
                                                   const float* __restrict__ SQ,
                                                   float* __restrict__ DT) {
    __shared__ float As[32][132];
    __shared__ float Bs[32][132];
    const int t = threadIdx.x;
    const int tx = t & 15, ty = t >> 4;
    int bid = blockIdx.x;
    int bi = 0;
    while (bid >= 16 - bi) { bid -= 16 - bi; ++bi; }
    const int bj = bi + bid;
    const int i0 = bi * 128;
    const int j0 = bj * 128;
    const int z = blockIdx.z;
    const float* Xb = X + (size_t)z * NPTS * DIN;
    const float* SQb = SQ + (size_t)z * NPTS;
    float* DTb = DT + (size_t)z * NPTS * NPTS;

    const int e = t & 127;

    float acc[8][8];
    #pragma unroll
    for (int i = 0; i < 8; ++i)
        #pragma unroll
        for (int j = 0; j < 8; ++j) acc[i][j] = 0.f;

    {
        const int rh = (t >> 7) * 8;
        #pragma unroll
        for (int i = 0; i < 8; ++i) {
            int k = rh + i;
            As[rh + i][e] = (k < DIN) ? Xb[(size_t)(i0 + e) * DIN + k] : 0.f;
            Bs[rh + i][e] = (k < DIN) ? Xb[(size_t)(j0 + e) * DIN + k] : 0.f;
        }
        __syncthreads();
        #pragma unroll
        for (int r = 0; r < 16; ++r) {
            float4 a0 = *(const float4*)&As[r][ty * 4];
            float4 a1 = *(const float4*)&As[r][64 + ty * 4];
            float4 b0 = *(const float4*)&Bs[r][tx * 4];
            float4 b1 = *(const float4*)&Bs[r][64 + tx * 4];
            float av[8] = {a0.x, a0.y, a0.z, a0.w, a1.x, a1.y, a1.z, a1.w};
            float bv[8] = {b0.x, b0.y, b0.z, b0.w, b1.x, b1.y, b1.z, b1.w};
            #pragma unroll
            for (int i = 0; i < 8; ++i)
                #pragma unroll
                for (int j = 0; j < 8; ++j)
                    acc[i][j] = fmaf(av[i], bv[j], acc[i][j]);
        }
        __syncthreads();
    }

    float sqi[8], sqj[8];
    #pragma unroll
    for (int i = 0; i < 8; ++i) {
        int ro = (i < 4) ? (ty * 4 + i) : (64 + ty * 4 + (i - 4));
        sqi[i] = SQb[i0 + ro];
    }
    #pragma unroll
    for (int j = 0; j < 8; ++j) {
        int co = (j < 4) ? (tx * 4 + j) : (64 + tx * 4 + (j - 4));
        sqj[j] = SQb[j0 + co];
    }
    #pragma unroll
    for (int i = 0; i < 8; ++i) {
        int ro = (i < 4) ? (ty * 4 + i) : (64 + ty * 4 + (i - 4));
        float* out = DTb + (size_t)(i0 + ro) * NPTS + j0;
        float4 o0, o1;
        o0.x = (sqi[i] + sqj[0]) - 2.f * acc[i][0];
        o0.y = (sqi[i] + sqj[1]) - 2.f * acc[i][1];
        o0.z = (sqi[i] + sqj[2]) - 2.f * acc[i][2];
        o0.w = (sqi[i] + sqj[3]) - 2.f * acc[i][3];
        o1.x = (sqi[i] + sqj[4]) - 2.f * acc[i][4];
        o1.y = (sqi[i] + sqj[5]) - 2.f * acc[i][5];
        o1.z = (sqi[i] + sqj[6]) - 2.f * acc[i][6];
        o1.w = (sqi[i] + sqj[7]) - 2.f * acc[i][7];
        *(float4*)(out + tx * 4) = o0;
        *(float4*)(out + 64 + tx * 4) = o1;
    }
    if (bi != bj) {
        #pragma unroll
        for (int j = 0; j < 8; ++j) {
            int co = (j < 4) ? (tx * 4 + j) : (64 + tx * 4 + (j - 4));
            float* out = DTb + (size_t)(j0 + co) * NPTS + i0;
            float4 o0, o1;
            o0.x = (sqi[0] + sqj[j]) - 2.f * acc[0][j];
            o0.y = (sqi[1] + sqj[j]) - 2.f * acc[1][j];
            o0.z = (sqi[2] + sqj[j]) - 2.f * acc[2][j];
            o0.w = (sqi[3] + sqj[j]) - 2.f * acc[3][j];
            o1.x = (sqi[4] + sqj[j]) - 2.f * acc[4][j];
            o1.y = (sqi[5] + sqj[j]) - 2.f * acc[5][j];
            o1.z = (sqi[6] + sqj[j]) - 2.f * acc[6][j];
            o1.w = (sqi[7] + sqj[j]) - 2.f * acc[7][j];
            *(float4*)(out + ty * 4) = o0;
            *(float4*)(out + 64 + ty * 4) = o1;
        }
    }
}

// ======== gram MFMA (DIN%32==0): f16x3, full 16x16 tile grid, coalesced writes ======
template <int DIN>
__global__ __launch_bounds__(256) void gram_mfma_kernel(const float* __restrict__ X,
                                                        const float* __restrict__ SQ,
                                                        float* __restrict__ DT) {
    __shared__ _Float16 Ah[128][40];
    __shared__ _Float16 Al[128][40];
    __shared__ _Float16 Bh[128][40];
    __shared__ _Float16 Bl[128][40];
    const int t = threadIdx.x;
    const int bi = blockIdx.x >> 4, bj = blockIdx.x & 15;
    const int i0 = bi * 128, j0 = bj * 128;
    const int z = blockIdx.z;
    const float* Xb = X + (size_t)z * NPTS * DIN;
    const float* SQb = SQ + (size_t)z * NPTS;
    float* DTb = DT + (size_t)z * NPTS * NPTS;

    const int e = t & 127;
    const int rh = (t >> 7) * 16;   // k-half 0 or 16
    const float* Ar = Xb + (size_t)(i0 + e) * DIN + rh;
    const float* Br = Xb + (size_t)(j0 + e) * DIN + rh;

    const int w = t >> 6;
    const int lane = t & 63;
    const int wr = (w >> 1) * 64;
    const int wc = (w & 1) * 64;
    const int lr = lane & 31;
    const int lk = (lane >> 5) * 8;
    const int hsel = lane >> 5;

    floatx16 acc[2][2];
    #pragma unroll
    for (int i = 0; i < 2; ++i)
        #pragma unroll
        for (int j = 0; j < 2; ++j)
            #pragma unroll
            for (int r = 0; r < 16; ++r) acc[i][j][r] = 0.f;

    for (int k0 = 0; k0 < DIN; k0 += 32) {
        #pragma unroll
        for (int h = 0; h < 4; ++h) {
            float4 a = *(const float4*)(Ar + k0 + h * 4);
            float4 b = *(const float4*)(Br + k0 + h * 4);
            _Float16 ah0 = (_Float16)a.x, ah1 = (_Float16)a.y, ah2 = (_Float16)a.z, ah3 = (_Float16)a.w;
            half4 av, alv;
            av.x = ah0; av.y = ah1; av.z = ah2; av.w = ah3;
            alv.x = (_Float16)(a.x - (float)ah0);
            alv.y = (_Float16)(a.y - (float)ah1);
            alv.z = (_Float16)(a.z - (float)ah2);
            alv.w = (_Float16)(a.w - (float)ah3);
            *(half4*)&Ah[e][rh + h * 4] = av;
            *(half4*)&Al[e][rh + h * 4] = alv;
            _Float16 bh0 = (_Float16)b.x, bh1 = (_Float16)b.y, bh2 = (_Float16)b.z, bh3 = (_Float16)b.w;
            half4 bv, blv;
            bv.x = bh0; bv.y = bh1; bv.z = bh2; bv.w = bh3;
            blv.x = (_Float16)(b.x - (float)bh0);
            blv.y = (_Float16)(b.y - (float)bh1);
            blv.z = (_Float16)(b.z - (float)bh2);
            blv.w = (_Float16)(b.w - (float)bh3);
            *(half4*)&Bh[e][rh + h * 4] = bv;
            *(half4*)&Bl[e][rh + h * 4] = blv;
        }
        __syncthreads();
        #pragma unroll
        for (int ks = 0; ks < 2; ++ks) {
            const int kb = ks * 16 + lk;
            half8 bf0  = *(const half8*)&Bh[wc + lr][kb];
            half8 blf0 = *(const half8*)&Bl[wc + lr][kb];
            half8 bf1  = *(const half8*)&Bh[wc + 32 + lr][kb];
            half8 blf1 = *(const half8*)&Bl[wc + 32 + lr][kb];
            #pragma unroll
            for (int i = 0; i < 2; ++i) {
                half8 af  = *(const half8*)&Ah[wr + i * 32 + lr][kb];
                half8 alf = *(const half8*)&Al[wr + i * 32 + lr][kb];
                acc[i][0] = __builtin_amdgcn_mfma_f32_32x32x16_f16(af,  bf0,  acc[i][0], 0, 0, 0);
                acc[i][0] = __builtin_amdgcn_mfma_f32_32x32x16_f16(af,  blf0, acc[i][0], 0, 0, 0);
                acc[i][0] = __builtin_amdgcn_mfma_f32_32x32x16_f16(alf, bf0,  acc[i][0], 0, 0, 0);
                acc[i][1] = __builtin_amdgcn_mfma_f32_32x32x16_f16(af,  bf1,  acc[i][1], 0, 0, 0);
                acc[i][1] = __builtin_amdgcn_mfma_f32_32x32x16_f16(af,  blf1, acc[i][1], 0, 0, 0);
                acc[i][1] = __builtin_amdgcn_mfma_f32_32x32x16_f16(alf, bf1,  acc[i][1], 0, 0, 0);
            }
        }
        __syncthreads();
    }

    const float sqj0 = SQb[j0 + wc + lr];
    const float sqj1 = SQb[j0 + wc + 32 + lr];
    #pragma unroll
    for (int i = 0; i < 2; ++i) {
        #pragma unroll
        for (int r = 0; r < 16; ++r) {
            const int row = wr + i * 32 + (r & 3) + 8 * (r >> 2) + 4 * hsel;
            const float sqi = SQb[i0 + row];
            float* out = DTb + (size_t)(i0 + row) * NPTS + j0 + wc;
            out[lr]      = (sqi + sqj0) - 2.f * acc[i][0][r];
            out[32 + lr] = (sqi + sqj1) - 2.f * acc[i][1][r];
        }
    }
}

// ---------------- knn select: one query per wave, dists in registers ----------------
__global__ __launch_bounds__(256) void knn_select_kernel(const float* __restrict__ DT,
                                                         int* __restrict__ IDX, int qoff) {
    const int t = threadIdx.x;
    const int w = t >> 6, lane = t & 63;
    const int q = blockIdx.x * 4 + w;
    const float* dq = DT + (size_t)q * NPTS;
    const int l4 = lane << 2;

    float vals[32];
    #pragma unroll
    for (int s = 0; s < 8; ++s) {
        float4 v = *(const float4*)(dq + s * 256 + l4);
        vals[s * 4 + 0] = v.x; vals[s * 4 + 1] = v.y;
        vals[s * 4 + 2] = v.z; vals[s * 4 + 3] = v.w;
    }
    unsigned rm = 0;
    float best = INFINITY; int bslot = 32;
    #pragma unroll
    for (int sl = 0; sl < 32; ++sl)
        if (vals[sl] < best) { best = vals[sl]; bslot = sl; }

    for (int rep = 0; rep < KNN; ++rep) {
        int bj = (bslot < 32) ? ((bslot >> 2) * 256 + l4 + (bslot & 3)) : NPTS;
        float gb = best; int gj = bj;
        #pragma unroll
        for (int off = 1; off < 64; off <<= 1) {
            float ov = __shfl_xor(gb, off);
            int oj = __shfl_xor(gj, off);
            if (ov < gb || (ov == gb && oj < gj)) { gb = ov; gj = oj; }
        }
        if (lane == 0) IDX[(size_t)(qoff + q) * KNN + rep] = gj;
        if (((gj >> 2) & 63) == lane) {
            int slot = ((gj >> 8) << 2) | (gj & 3);
            rm |= (1u << slot);
            best = INFINITY; bslot = 32;
            #pragma unroll
            for (int sl = 0; sl < 32; ++sl)
                if (!(rm & (1u << sl)) && vals[sl] < best) { best = vals[sl]; bslot = sl; }
        }
    }
}

// ---------------- gemm big: C[M,N] = A[M,K]@B[K,N] + bias, 128x128, BK=32, plain -----
template <int KK, int NN>
__global__ __launch_bounds__(256) void gemm_big_kernel(const float* __restrict__ A,
                                                       const float* __restrict__ B,
                                                       const float* __restrict__ bias,
                                                       float* __restrict__ C) {
    __shared__ float As[32][132];
    __shared__ float Bs[32][132];
    const int t = threadIdx.x;
    const int tx = t & 15, ty = t >> 4;
    const int m0 = blockIdx.x * 128;
    const int c0 = blockIdx.y * 128;

    float acc[8][8];
    #pragma unroll
    for (int i = 0; i < 8; ++i)
        #pragma unroll
        for (int j = 0; j < 8; ++j) acc[i][j] = 0.f;

    const int e = t & 127;
    const int rh = (t >> 7) * 16;
    const float* Ar = A + (size_t)(m0 + e) * KK + rh;
    const int br = t & 31;
    const int bc = (t >> 5) * 16;
    const float* Wbase = B + (size_t)br * NN + c0 + bc;

    for (int k0 = 0; k0 < KK; k0 += 32) {
        #pragma unroll
        for (int h = 0; h < 4; ++h) {
            float4 a = *(const float4*)(Ar + k0 + h * 4);
            As[rh + h * 4 + 0][e] = a.x; As[rh + h * 4 + 1][e] = a.y;
            As[rh + h * 4 + 2][e] = a.z; As[rh + h * 4 + 3][e] = a.w;
            *(float4*)&Bs[br][bc + h * 4] = *(const float4*)(Wbase + (size_t)k0 * NN + h * 4);
        }
        __syncthreads();
        #pragma unroll
        for (int r = 0; r < 32; ++r) {
            float4 a0 = *(const float4*)&As[r][ty * 4];
            float4 a1 = *(const float4*)&As[r][64 + ty * 4];
            float4 b0 = *(const float4*)&Bs[r][tx * 4];
            float4 b1 = *(const float4*)&Bs[r][64 + tx * 4];
            float av[8] = {a0.x, a0.y, a0.z, a0.w, a1.x, a1.y, a1.z, a1.w};
            float bv[8] = {b0.x, b0.y, b0.z, b0.w, b1.x, b1.y, b1.z, b1.w};
            #pragma unroll
            for (int i = 0; i < 8; ++i)
                #pragma unroll
                for (int j = 0; j < 8; ++j)
                    acc[i][j] = fmaf(av[i], bv[j], acc[i][j]);
        }
        __syncthreads();
    }

    float bvv[8];
    #pragma unroll
    for (int j = 0; j < 8; ++j) {
        int co = (j < 4) ? (tx * 4 + j) : (64 + tx * 4 + (j - 4));
        bvv[j] = bias[c0 + co];
    }
    #pragma unroll
    for (int i = 0; i < 8; ++i) {
        int ro = (i < 4) ? (ty * 4 + i) : (64 + ty * 4 + (i - 4));
        float* out = C + (size_t)(m0 + ro) * NN + c0;
        float4 o0, o1;
        o0.x = acc[i][0] + bvv[0]; o0.y = acc[i][1] + bvv[1];
        o0.z = acc[i][2] + bvv[2]; o0.w = acc[i][3] + bvv[3];
        o1.x = acc[i][4] + bvv[4]; o1.y = acc[i][5] + bvv[5];
        o1.z = acc[i][6] + bvv[6]; o1.w = acc[i][7] + bvv[7];
        *(float4*)(out + tx * 4) = o0;
        *(float4*)(out + 64 + tx * 4) = o1;
    }
}

// ---------------- generic tiled GEMM (fallback, 64x64): C = A@B + bias ----------------
template <int KK, int NN>
__global__ __launch_bounds__(256) void gemm_pq_kernel(const float* __restrict__ A,
                                                      const float* __restrict__ B,
                                                      const float* __restrict__ bias,
                                                      float* __restrict__ C) {
    __shared__ float As[16][68];
    __shared__ float Bs[16][64];
    const int t = threadIdx.x;
    const int tx = t & 15, ty = t >> 4;
    const int m0 = blockIdx.x * 64;
    const int c0 = blockIdx.y * 64;
    float acc[4][4];
    #pragma unroll
    for (int i = 0; i < 4; ++i)
        #pragma unroll
        for (int j = 0; j < 4; ++j) acc[i][j] = 0.f;

    constexpr int KCH = (KK + 15) / 16;
    for (int kc = 0; kc < KCH; ++kc) {
        const int k0 = kc * 16;
        {
            int m = t & 63;
            int r4 = (t >> 6) * 4;
            if constexpr (KK % 16 == 0) {
                float4 v = *(const float4*)(A + (size_t)(m0 + m) * KK + k0 + r4);
                As[r4 + 0][m] = v.x; As[r4 + 1][m] = v.y;
                As[r4 + 2][m] = v.z; As[r4 + 3][m] = v.w;
            } else {
                #pragma unroll
                for (int i = 0; i < 4; ++i) {
                    int r = r4 + i;
                    As[r][m] = (k0 + r < KK) ? A[(size_t)(m0 + m) * KK + k0 + r] : 0.f;
                }
            }
        }
        {
            int r = t >> 4;
            int c = (t & 15) * 4;
            float4 v = make_float4(0.f, 0.f, 0.f, 0.f);
            if (k0 + r < KK) v = *(const float4*)(B + (size_t)(k0 + r) * NN + c0 + c);
            *(float4*)&Bs[r][c] = v;
        }
        __syncthreads();
        #pragma unroll
        for (int r = 0; r < 16; ++r) {
            float4 a4 = *(const float4*)&As[r][ty * 4];
            float4 b4 = *(const float4*)&Bs[r][tx * 4];
            float av[4] = {a4.x, a4.y, a4.z, a4.w};
            float bv[4] = {b4.x, b4.y, b4.z, b4.w};
            #pragma unroll
            for (int i = 0; i < 4; ++i)
                #pragma unroll
                for (int j = 0; j < 4; ++j)
                    acc[i][j] = fmaf(av[i], bv[j], acc[i][j]);
        }
        __syncthreads();
    }
    float4 bv4 = *(const float4*)(bias + c0 + tx * 4);
    float bv[4] = {bv4.x, bv4.y, bv4.z, bv4.w};
    #pragma unroll
    for (int i = 0; i < 4; ++i) {
        float4 o;
        o.x = acc[i][0] + bv[0];
        o.y = acc[i][1] + bv[1];
        o.z = acc[i][2] + bv[2];
        o.w = acc[i][3] + bv[3];
        *(float4*)(C + (size_t)(m0 + ty * 4 + i) * NN + c0 + tx * 4) = o;
    }
}

// ---------------- edge small (DOUT<=32): 64 edges x 64 cols, 4x4/thread ----------
template <int D2, int DOUT>
__global__ __launch_bounds__(256) void edge_kernel(const float* __restrict__ PQ,
                                                   const int* __restrict__ IDX,
                                                   const float* __restrict__ W2,
                                                   const float* __restrict__ b2,
                                                   float* __restrict__ Xn) {
    constexpr int N4 = 2 * D2;
    __shared__ float As[16][68];
    __shared__ float Bs[16][64];
    __shared__ int gjs[64];
    const int t = threadIdx.x;
    const int tx = t & 15, ty = t >> 4;
    const int nb = blockIdx.x * 4;
    const int c0 = blockIdx.y * 64;

    if (t < 64) {
        int node = nb + (t >> 4);
        int bstart = (node / NPTS) * NPTS;
        gjs[t] = bstart + IDX[(size_t)node * KNN + (t & 15)];
    }
    __syncthreads();

    float acc[4][4];
    #pragma unroll
    for (int i = 0; i < 4; ++i)
        #pragma unroll
        for (int j = 0; j < 4; ++j) acc[i][j] = 0.f;

    const int e = t & 63;
    const int r4 = (t >> 6) * 4;
    const int gi = nb + (e >> 4);

    for (int k0 = 0; k0 < D2; k0 += 16) {
        {
            int gj = gjs[e];
            float4 p = *(const float4*)(PQ + (size_t)gi * N4 + k0 + r4);
            float4 q = *(const float4*)(PQ + (size_t)gj * N4 + D2 + k0 + r4);
            As[r4 + 0][e] = fmaxf(p.x + q.x, 0.f);
            As[r4 + 1][e] = fmaxf(p.y + q.y, 0.f);
            As[r4 + 2][e] = fmaxf(p.z + q.z, 0.f);
            As[r4 + 3][e] = fmaxf(p.w + q.w, 0.f);
        }
        {
            int r = t >> 4;
            int c = (t & 15) * 4;
            float4 v = make_float4(0.f, 0.f, 0.f, 0.f);
            if (c0 + c < DOUT) v = *(const float4*)(W2 + (size_t)(k0 + r) * DOUT + c0 + c);
            *(float4*)&Bs[r][c] = v;
        }
        __syncthreads();
        #pragma unroll
        for (int r = 0; r < 16; ++r) {
            float4 a4 = *(const float4*)&As[r][ty * 4];
            float4 b4 = *(const float4*)&Bs[r][tx * 4];
            float av[4] = {a4.x, a4.y, a4.z, a4.w};
            float bv[4] = {b4.x, b4.y, b4.z, b4.w};
            #pragma unroll
            for (int i = 0; i < 4; ++i)
                #pragma unroll
                for (int j = 0; j < 4; ++j)
                    acc[i][j] = fmaf(av[i], bv[j], acc[i][j]);
        }
        __syncthreads();
    }

    float bv[4];
    #pragma unroll
    for (int j = 0; j < 4; ++j) {
        int c = c0 + tx * 4 + j;
        bv[j] = (c < DOUT) ? b2[c] : 0.f;
    }
    float s[4];
    #pragma unroll
    for (int j = 0; j < 4; ++j) {
        float ss = 0.f;
        #pragma unroll
        for (int i = 0; i < 4; ++i) ss += fmaxf(acc[i][j] + bv[j], 0.f);
        s[j] = ss;
    }
    #pragma unroll
    for (int j = 0; j < 4; ++j) Bs[ty][tx * 4 + j] = s[j];
    __syncthreads();
    if ((ty & 3) == 0) {
        int node = nb + (ty >> 2);
        #pragma unroll
        for (int j = 0; j < 4; ++j) {
            int c = c0 + tx * 4 + j;
            if (c < DOUT) {
                int cc = tx * 4 + j;
                float tot = Bs[ty][cc] + Bs[ty + 1][cc] + Bs[ty + 2][cc] + Bs[ty + 3][cc];
                Xn[(size_t)node * DOUT + c] = tot * (1.f / 16.f);
            }
        }
    }
}

// ======== edge big (DOUT>=128): f16x3 MFMA, A+B LDS DOUBLE-BUFFER, 1 barrier/K-step ==
// (round-8 proven best: 311us, MfmaUtil 29.5%)
#define EBG_LOAD(KN)                                                                 \
  { _Pragma("unroll")                                                                \
    for (int h = 0; h < 4; ++h) {                                                    \
      pp[h] = *(const float4*)(Prow + (KN) + rh + h * 4);                            \
      qq[h] = *(const float4*)(Qrow + (KN) + rh + h * 4);                            \
    }                                                                                \
    wh = *(const half8*)(WHrow + (KN));                                              \
    wl = *(const half8*)(WLrow + (KN)); }

#define EBG_STAGE(dst)                                                               \
  { _Pragma("unroll")                                                                \
    for (int h = 0; h < 4; ++h) {                                                    \
      float a0 = fmaxf(pp[h].x + qq[h].x, 0.f);                                      \
      float a1 = fmaxf(pp[h].y + qq[h].y, 0.f);                                      \
      float a2 = fmaxf(pp[h].z + qq[h].z, 0.f);                                      \
      float a3 = fmaxf(pp[h].w + qq[h].w, 0.f);                                      \
      _Float16 h0 = (_Float16)a0, h1 = (_Float16)a1;                                 \
      _Float16 h2 = (_Float16)a2, h3 = (_Float16)a3;                                 \
      half4 hv, lv;                                                                  \
      hv.x = h0; hv.y = h1; hv.z = h2; hv.w = h3;                                    \
      lv.x = (_Float16)(a0 - (float)h0);                                             \
      lv.y = (_Float16)(a1 - (float)h1);                                             \
      lv.z = (_Float16)(a2 - (float)h2);                                             \
      lv.w = (_Float16)(a3 - (float)h3);                                             \
      *(half4*)&Ah[dst][e][rh + h * 4] = hv;                                         \
      *(half4*)&Al[dst][e][rh + h * 4] = lv;                                         \
    }                                                                                \
    *(half8*)&Bh[dst][eb][rb] = wh;                                                  \
    *(half8*)&Bl[dst][eb][rb] = wl; }

#define EBG_MFMA(cur)                                                                \
  { _Pragma("unroll")                                                                \
    for (int ks = 0; ks < 2; ++ks) {                                                 \
      const int kb = ks * 16 + lk;                                                   \
      half8 bf0  = *(const half8*)&Bh[cur][wc + lr][kb];                             \
      half8 blf0 = *(const half8*)&Bl[cur][wc + lr][kb];                             \
      half8 bf1  = *(const half8*)&Bh[cur][wc + 32 + lr][kb];                        \
      half8 blf1 = *(const half8*)&Bl[cur][wc + 32 + lr][kb];                        \
      _Pragma("unroll")                                                              \
      for (int i = 0; i < 2; ++i) {                                                  \
        half8 af  = *(const half8*)&Ah[cur][wr + i * 32 + lr][kb];                   \
        half8 alf = *(const half8*)&Al[cur][wr + i * 32 + lr][kb];                   \
        acc[i][0] = __builtin_amdgcn_mfma_f32_32x32x16_f16(af,  bf0,  acc[i][0], 0, 0, 0); \
        acc[i][0] = __builtin_amdgcn_mfma_f32_32x32x16_f16(af,  blf0, acc[i][0], 0, 0, 0); \
        acc[i][0] = __builtin_amdgcn_mfma_f32_32x32x16_f16(alf, bf0,  acc[i][0], 0, 0, 0); \
        acc[i][1] = __builtin_amdgcn_mfma_f32_32x32x16_f16(af,  bf1,  acc[i][1], 0, 0, 0); \
        acc[i][1] = __builtin_amdgcn_mfma_f32_32x32x16_f16(af,  blf1, acc[i][1], 0, 0, 0); \
        acc[i][1] = __builtin_amdgcn_mfma_f32_32x32x16_f16(alf, bf1,  acc[i][1], 0, 0, 0); \
      }                                                                              \
    } }

template <int D2, int DOUT>
__global__ __launch_bounds__(512) void edge_big_mfma_kernel(const float* __restrict__ PQ,
                                                            const int* __restrict__ IDX,
                                                            const _Float16* __restrict__ W2H,
                                                            const _Float16* __restrict__ W2L,
                                                            const float* __restrict__ b2,
                                                            float* __restrict__ Xn) {
    constexpr int N4 = 2 * D2;
    constexpr int NSTEP = D2 / 32;
    __shared__ _Float16 Ah[2][256][40];
    __shared__ _Float16 Al[2][256][40];
    __shared__ _Float16 Bh[2][128][40];
    __shared__ _Float16 Bl[2][128][40];
    __shared__ int gjs[256];
    const int t = threadIdx.x;
    const int nb16 = blockIdx.x * 16;
    const int c0 = blockIdx.y * 128;

    if (t < 256) {
        int node = nb16 + (t >> 4);
        int bstart = (node / NPTS) * NPTS;
        gjs[t] = bstart + IDX[(size_t)node * KNN + (t & 15)];
    }
    __syncthreads();

    const int e  = t & 255;
    const int rh = (t >> 8) * 16;
    const int gi = nb16 + (e >> 4);
    const int gj = gjs[e];
    const float* Prow = PQ + (size_t)gi * N4;
    const float* Qrow = PQ + (size_t)gj * N4 + D2;
    const int eb = t & 127;
    const int rb = (t >> 7) * 8;
    const _Float16* WHrow = W2H + (size_t)(c0 + eb) * D2 + rb;
    const _Float16* WLrow = W2L + (size_t)(c0 + eb) * D2 + rb;

    const int w = t >> 6;
    const int lane = t & 63;
    const int wr = (w >> 1) * 64;
    const int wc = (w & 1) * 64;
    const int lr = lane & 31;
    const int lk = (lane >> 5) * 8;
    const int hsel = lane >> 5;

    floatx16 acc[2][2];
    #pragma unroll
    for (int i = 0; i < 2; ++i)
        #pragma unroll
        for (int j = 0; j < 2; ++j)
            #pragma unroll
            for (int r = 0; r < 16; ++r) acc[i][j][r] = 0.f;

    float4 pp[4], qq[4];
    half8 wh, wl;

    EBG_LOAD(0)
    EBG_STAGE(0)
    EBG_LOAD(32)
    asm volatile("s_waitcnt lgkmcnt(0)" ::: "memory");
    __builtin_amdgcn_s_barrier();
    asm volatile("" ::: "memory");

    for (int s = 0; s < NSTEP - 1; ++s) {
        const int cur = s & 1;
        EBG_MFMA(cur)
        EBG_STAGE(cur ^ 1)
        const int kn = (s + 2 < NSTEP) ? (s + 2) * 32 : (NSTEP - 1) * 32;
        EBG_LOAD(kn)
        asm volatile("s_waitcnt lgkmcnt(0)" ::: "memory");
        __builtin_amdgcn_s_barrier();
        asm volatile("" ::: "memory");
    }
    EBG_MFMA((NSTEP - 1) & 1)

    float bb[2];
    bb[0] = b2[c0 + wc + lr];
    bb[1] = b2[c0 + wc + 32 + lr];
    #pragma unroll
    for (int i = 0; i < 2; ++i) {
        int node0 = nb16 + ((wr + i * 32) >> 4);
        #pragma unroll
        for (int j = 0; j < 2; ++j) {
            float sA = 0.f, sB = 0.f;
            #pragma unroll
            for (int r = 0; r < 8; ++r)  sA += fmaxf(acc[i][j][r] + bb[j], 0.f);
            #pragma unroll
            for (int r = 8; r < 16; ++r) sB += fmaxf(acc[i][j][r] + bb[j], 0.f);
            sA += __shfl_xor(sA, 32);
            sB += __shfl_xor(sB, 32);
            if (hsel == 0) {
                int col = c0 + wc + j * 32 + lr;
                Xn[(size_t)node0 * DOUT + col] = sA * (1.f / 16.f);
                Xn[(size_t)(node0 + 1) * DOUT + col] = sB * (1.f / 16.f);
            }
        }
    }
}
#undef EBG_LOAD
#undef EBG_STAGE
#undef EBG_MFMA

// ======== edge mid (DOUT==64): f16x3 MFMA, A+B LDS dbuf, single barrier/K-step ======
// Structural clone of the proven edge_big schedule with a 64-col B tile. Same per-acc
// MFMA order as the round-4 edge_mid -> bit-exact. LDS ~62 KB -> 2 blocks/CU.
#define EMD_LOAD(KN)                                                                 \
  { _Pragma("unroll")                                                                \
    for (int h = 0; h < 4; ++h) {                                                    \
      pp[h] = *(const float4*)(Prow + (KN) + rh + h * 4);                            \
      qq[h] = *(const float4*)(Qrow + (KN) + rh + h * 4);                            \
    }                                                                                \
    wh = *(const half8*)(WHrow + (KN));                                              \
    wl = *(const half8*)(WLrow + (KN)); }

#define EMD_STAGE(dst)                                                               \
  { _Pragma("unroll")                                                                \
    for (int h = 0; h < 4; ++h) {                                                    \
      float a0 = fmaxf(pp[h].x + qq[h].x, 0.f);                                      \
      float a1 = fmaxf(pp[h].y + qq[h].y, 0.f);                                      \
      float a2 = fmaxf(pp[h].z + qq[h].z, 0.f);                                      \
      float a3 = fmaxf(pp[h].w + qq[h].w, 0.f);                                      \
      _Float16 h0 = (_Float16)a0, h1 = (_Float16)a1;                                 \
      _Float16 h2 = (_Float16)a2, h3 = (_Float16)a3;                                 \
      half4 hv, lv;                                                                  \
      hv.x = h0; hv.y = h1; hv.z = h2; hv.w = h3;                                    \
      lv.x = (_Float16)(a0 - (float)h0);                                             \
      lv.y = (_Float16)(a1 - (float)h1);                                             \
      lv.z = (_Float16)(a2 - (float)h2);                                             \
      lv.w = (_Float16)(a3 - (float)h3);                                             \
      *(half4*)&Ah[dst][e][rh + h * 4] = hv;                                         \
      *(half4*)&Al[dst][e][rh + h * 4] = lv;                                         \
    }                                                                                \
    *(half8*)&Bh[dst][wrB][wkB] = wh;                                                \
    *(half8*)&Bl[dst][wrB][wkB] = wl; }

#define EMD_MFMA(cur)                                                                \
  { _Pragma("unroll")                                                                \
    for (int ks = 0; ks < 2; ++ks) {                                                 \
      const int kb = ks * 16 + lk;                                                   \
      half8 bf0  = *(const half8*)&Bh[cur][wc + lr][kb];                             \
      half8 blf0 = *(const half8*)&Bl[cur][wc + lr][kb];                             \
      _Pragma("unroll")                                                              \
      for (int i = 0; i < 2; ++i) {                                                  \
        half8 af  = *(const half8*)&Ah[cur][wr + i * 32 + lr][kb];                   \
        half8 alf = *(const half8*)&Al[cur][wr + i * 32 + lr][kb];                   \
        acc[i] = __builtin_amdgcn_mfma_f32_32x32x16_f16(af,  bf0,  acc[i], 0, 0, 0); \
        acc[i] = __builtin_amdgcn_mfma_f32_32x32x16_f16(af,  blf0, acc[i], 0, 0, 0); \
        acc[i] = __builtin_amdgcn_mfma_f32_32x32x16_f16(alf, bf0,  acc[i], 0, 0, 0); \
      }                                                                              \
    } }

template <int D2, int DOUT>
__global__ __launch_bounds__(256) void edge_mid_mfma_kernel(const float* __restrict__ PQ,
                                                            const int* __restrict__ IDX,
                                                            const _Float16* __restrict__ W2H,
                                                            const _Float16* __restrict__ W2L,
                                                            const float* __restrict__ b2,
                                                            float* __restrict__ Xn) {
    constexpr int N4 = 2 * D2;
    constexpr int NSTEP = D2 / 32;   // 4
    __shared__ _Float16 Ah[2][128][40];
    __shared__ _Float16 Al[2][128][40];
    __shared__ _Float16 Bh[2][64][40];
    __shared__ _Float16 Bl[2][64][40];
    __shared__ int gjs[128];
    const int t = threadIdx.x;
    const int nb8 = blockIdx.x * 8;

    if (t < 128) {
        int node = nb8 + (t >> 4);
        int bstart = (node / NPTS) * NPTS;
        gjs[t] = bstart + IDX[(size_t)node * KNN + (t & 15)];
    }
    __syncthreads();

    const int e = t & 127;
    const int rh = (t >> 7) * 16;
    const int gi = nb8 + (e >> 4);
    const int gj = gjs[e];
    const float* Prow = PQ + (size_t)gi * N4;
    const float* Qrow = PQ + (size_t)gj * N4 + D2;
    const int wrB = t & 63;            // B col (0..63)
    const int wkB = (t >> 6) * 8;      // k sub (0,8,16,24)
    const _Float16* WHrow = W2H + (size_t)wrB * D2 + wkB;
    const _Float16* WLrow = W2L + (size_t)wrB * D2 + wkB;

    const int w = t >> 6;
    const int lane = t & 63;
    const int wr = (w >> 1) * 64;
    const int wc = (w & 1) * 32;
    const int lr = lane & 31;
    const int lk = (lane >> 5) * 8;
    const int hsel = lane >> 5;

    floatx16 acc[2];
    #pragma unroll
    for (int i = 0; i < 2; ++i)
        #pragma unroll
        for (int r = 0; r < 16; ++r) acc[i][r] = 0.f;

    float4 pp[4], qq[4];
    half8 wh, wl;

    EMD_LOAD(0)
    EMD_STAGE(0)
    EMD_LOAD(32)
    asm volatile("s_waitcnt lgkmcnt(0)" ::: "memory");
    __builtin_amdgcn_s_barrier();
    asm volatile("" ::: "memory");

    for (int s = 0; s < NSTEP - 1; ++s) {
        const int cur = s & 1;
        EMD_MFMA(cur)
        EMD_STAGE(cur ^ 1)
        const int kn = (s + 2 < NSTEP) ? (s + 2) * 32 : (NSTEP - 1) * 32;
        EMD_LOAD(kn)
        asm volatile("s_waitcnt lgkmcnt(0)" ::: "memory");
        __builtin_amdgcn_s_barrier();
        asm volatile("" ::: "memory");
    }
    EMD_MFMA((NSTEP - 1) & 1)

    float bb = b2[wc + lr];
    #pragma unroll
    for (int i = 0; i < 2; ++i) {
        int node0 = nb8 + ((wr + i * 32) >> 4);
        float sA = 0.f, sB = 0.f;
        #pragma unroll
        for (int r = 0; r < 8; ++r)  sA += fmaxf(acc[i][r] + bb, 0.f);
        #pragma unroll
        for (int r = 8; r < 16; ++r) sB += fmaxf(acc[i][r] + bb, 0.f);
        sA += __shfl_xor(sA, 32);
        sB += __shfl_xor(sB, 32);
        if (hsel == 0) {
            int col = wc + lr;
            Xn[(size_t)node0 * DOUT + col] = sA * (1.f / 16.f);
            Xn[(size_t)(node0 + 1) * DOUT + col] = sB * (1.f / 16.f);
        }
    }
}
#undef EMD_LOAD
#undef EMD_STAGE
#undef EMD_MFMA

// ---------------- final: mean over nodes + 16x2 projection ----------------
__global__ __launch_bounds__(256) void final_kernel(const float* __restrict__ X,
                                                    const float* __restrict__ Wf,
                                                    const float* __restrict__ bfin,
                                                    float* __restrict__ out) {
    __shared__ float red[16][17];
    __shared__ float pool[16];
    const int b = blockIdx.x;
    const int t = threadIdx.x;
    const int c = t & 15, rg = t >> 4;
    float s = 0.f;
    for (int n = rg; n < NPTS; n += 16) s += X[(size_t)(b * NPTS + n) * 16 + c];
    red[rg][c] = s;
    __syncthreads();
    if (t < 16) {
        float tot = 0.f;
        #pragma unroll
        for (int i = 0; i < 16; ++i) tot += red[i][t];
        pool[t] = tot * (1.f / NPTS);
    }
    __syncthreads();
    if (t < 2) {
        float a = bfin[t];
        #pragma unroll
        for (int cc = 0; cc < 16; ++cc) a = fmaf(pool[cc], Wf[cc * 2 + t], a);
        out[b * 2 + t] = a;
    }
}

// ---------------- per-layer driver ----------------
template <int DIN, int DOUT>
static void run_layer(const float* Xin, float* Xout, float* PQ, float* SQ, int* IDX,
                      float* WCAT, float* BCAT, _Float16* W2H, _Float16* W2L,
                      const float* W1, const float* b1, const float* W2, const float* b2,
                      hipStream_t stream) {
    constexpr int D2 = 2 * DOUT;
    constexpr int N4 = 2 * D2;
    constexpr int prep_blocks = (DIN * N4 + 255) / 256;
    constexpr int w2_blocks = (DOUT >= 64) ? ((D2 * DOUT + 255) / 256) : 0;
    sqprep_kernel<<<BN / 256 + prep_blocks + w2_blocks, 256, 0, stream>>>(
        Xin, SQ, W1, b1, WCAT, BCAT, DIN, D2, W2, W2H, W2L,
        (DOUT >= 64) ? DOUT : 0, prep_blocks);
    for (int h = 0; h < 2; ++h) {
        if constexpr (DIN % 32 == 0) {
            dim3 gg(256, 1, 4);   // full 16x16 tile grid, coalesced writes
            gram_mfma_kernel<DIN><<<gg, 256, 0, stream>>>(Xin + (size_t)h * 4 * NPTS * DIN,
                                                          SQ + (size_t)h * 4 * NPTS, PQ);
        } else {
            dim3 gg(136, 1, 4);   // triangular fp32 path (DIN=3)
            gram_kernel<DIN><<<gg, 256, 0, stream>>>(Xin + (size_t)h * 4 * NPTS * DIN,
                                                     SQ + (size_t)h * 4 * NPTS, PQ);
        }
        knn_select_kernel<<<2048, 256, 0, stream>>>(PQ, IDX, h * 8192);
    }
    if constexpr (N4 % 128 == 0 && DIN % 32 == 0) {
        dim3 g1(BN / 128, N4 / 128);
        gemm_big_kernel<DIN, N4><<<g1, 256, 0, stream>>>(Xin, WCAT, BCAT, PQ);
    } else {
        dim3 g1(BN / 64, N4 / 64);
        gemm_pq_kernel<DIN, N4><<<g1, 256, 0, stream>>>(Xin, WCAT, BCAT, PQ);
    }
    if constexpr (DOUT >= 128) {
        dim3 g2(BN / 16, DOUT / 128);
        edge_big_mfma_kernel<D2, DOUT><<<g2, 512, 0, stream>>>(PQ, IDX, W2H, W2L, b2, Xout);
    } else if constexpr (DOUT == 64) {
        dim3 g2(BN / 8, 1);
        edge_mid_mfma_kernel<D2, DOUT><<<g2, 256, 0, stream>>>(PQ, IDX, W2H, W2L, b2, Xout);
    } else {
        dim3 g2(BN / 4, (DOUT + 63) / 64);
        edge_kernel<D2, DOUT><<<g2, 256, 0, stream>>>(PQ, IDX, W2, b2, Xout);
    }
}

extern "C" void kernel_launch(void* const* d_in, const int* in_sizes, int n_in,
                              void* d_out, int out_size, void* d_ws, size_t ws_size,
                              hipStream_t stream) {
    (void)in_sizes; (void)n_in; (void)out_size; (void)ws_size;
    const float* x = (const float*)d_in[0];
    const float* W1a[6]; const float* b1a[6]; const float* W2a[6]; const float* b2a[6];
    for (int l = 0; l < 6; ++l) {
        W1a[l] = (const float*)d_in[1 + 4 * l];
        b1a[l] = (const float*)d_in[2 + 4 * l];
        W2a[l] = (const float*)d_in[3 + 4 * l];
        b2a[l] = (const float*)d_in[4 + 4 * l];
    }
    const float* Wf = (const float*)d_in[25];
    const float* bfin = (const float*)d_in[26];

    float* ws = (float*)d_ws;
    float* X0   = ws;                                   // 16384*256
    float* X1   = X0 + (size_t)BN * 256;                // 16384*256
    float* PQ   = X1 + (size_t)BN * 256;                // 16384*1024 (also knn DT)
    float* SQ   = PQ + (size_t)BN * 1024;               // 16384
    int*   IDX  = (int*)(SQ + BN);                      // 16384*16
    float* WCAT = (float*)(IDX + (size_t)BN * KNN);     // 131072
    float* BCAT = WCAT + 131072;                        // 1024
    _Float16* W2H = (_Float16*)(BCAT + 1024);           // 131072 halfs (256 KB)
    _Float16* W2L = W2H + 131072;                       // 131072 halfs (256 KB)

    run_layer<3,   32>(x,  X0, PQ, SQ, IDX, WCAT, BCAT, W2H, W2L, W1a[0], b1a[0], W2a[0], b2a[0], stream);
    run_layer<32, 128>(X0, X1, PQ, SQ, IDX, WCAT, BCAT, W2H, W2L, W1a[1], b1a[1], W2a[1], b2a[1], stream);
    run_layer<128,256>(X1, X0, PQ, SQ, IDX, WCAT, BCAT, W2H, W2L, W1a[2], b1a[2], W2a[2], b2a[2], stream);
    run_layer<256, 64>(X0, X1, PQ, SQ, IDX, WCAT, BCAT, W2H, W2L, W1a[3], b1a[3], W2a[3], b2a[3], stream);
    run_layer<64,  32>(X1, X0, PQ, SQ, IDX, WCAT, BCAT, W2H, W2L, W1a[4], b1a[4], W2a[4], b2a[4], stream);
    run_layer<32,  16>(X0, X1, PQ, SQ, IDX, WCAT, BCAT, W2H, W2L, W1a[5], b1a[5], W2a[5], b2a[5], stream);
    final_kernel<<<NB, 256, 0, stream>>>(X1, Wf, bfin, (float*)d_out);
}

// Round 11
// 1789.233 us; speedup vs baseline: 1.0391x; 1.0080x over previous
//
#include <hip/hip_runtime.h>
#include <math.h>

#define NPTS 2048
#define NB 8
#define BN 16384   // NB*NPTS
#define KNN 16

typedef _Float16 half4 __attribute__((ext_vector_type(4)));
typedef _Float16 half8 __attribute__((ext_vector_type(8)));
typedef float floatx16 __attribute__((ext_vector_type(16)));

// ---------------- fused sq + prep: sq | Wcat/bcat | W2 hi/lo split (transposed) ------
__global__ __launch_bounds__(256) void sqprep_kernel(const float* __restrict__ X,
                                                     float* __restrict__ SQ,
                                                     const float* __restrict__ W1,
                                                     const float* __restrict__ b1,
                                                     float* __restrict__ Wcat,
                                                     float* __restrict__ bcat,
                                                     int din, int d2,
                                                     const float* __restrict__ W2,
                                                     _Float16* __restrict__ W2H,
                                                     _Float16* __restrict__ W2L,
                                                     int dout, int pb) {
    const int bid = blockIdx.x;
    if (bid < BN / 256) {
        int g = bid * 256 + threadIdx.x;
        const float* row = X + (size_t)g * din;
        float s = 0.f;
        for (int d = 0; d < din; ++d) s = fmaf(row[d], row[d], s);
        SQ[g] = s;
    } else if (bid < BN / 256 + pb) {
        int n4 = 2 * d2;
        int total = din * n4;
        int i = (bid - BN / 256) * 256 + threadIdx.x;
        if (i < total) {
            int d = i / n4, c = i - d * n4;
            float v;
            if (c < d2) v = W1[d * d2 + c] - W1[(din + d) * d2 + c];
            else        v = W1[(din + d) * d2 + (c - d2)];
            Wcat[i] = v;
        }
        if (i < n4) bcat[i] = (i < d2) ? b1[i] : 0.f;
    } else {
        // W2 split: W2 is [d2][dout] fp32 -> W2H/W2L [dout][d2] f16 (hi + residual lo)
        int i = (bid - BN / 256 - pb) * 256 + threadIdx.x;
        if (i < d2 * dout) {
            int k = i / dout, c = i - k * dout;
            float wv = W2[i];
            _Float16 hv = (_Float16)wv;
            float rv = wv - (float)hv;
            W2H[(size_t)c * d2 + k] = hv;
            W2L[(size_t)c * d2 + k] = (_Float16)rv;
        }
    }
}

// ---------------- gram fp32 (DIN=3 only): triangular tile grid, mirror write ---------
template <int DIN>
__global__ __launch_bounds__(256) void gram_kernel(const float* __restrict__ X,
                                                   const float* __restrict__ SQ,
                                                   float* __restrict__ DT) {
    __shared__ float As[32][132];
    __shared__ float Bs[32][132];
    const int t = threadIdx.x;
    const int tx = t & 15, ty = t >> 4;
    int bid = blockIdx.x;
    int bi = 0;
    while (bid >= 16 - bi) { bid -= 16 - bi; ++bi; }
    const int bj = bi + bid;
    const int i0 = bi * 128;
    const int j0 = bj * 128;
    const int z = blockIdx.z;
    const float* Xb = X + (size_t)z * NPTS * DIN;
    const float* SQb = SQ + (size_t)z * NPTS;
    float* DTb = DT + (size_t)z * NPTS * NPTS;

    const int e = t & 127;

    float acc[8][8];
    #pragma unroll
    for (int i = 0; i < 8; ++i)
        #pragma unroll
        for (int j = 0; j < 8; ++j) acc[i][j] = 0.f;

    {
        const int rh = (t >> 7) * 8;
        #pragma unroll
        for (int i = 0; i < 8; ++i) {
            int k = rh + i;
            As[rh + i][e] = (k < DIN) ? Xb[(size_t)(i0 + e) * DIN + k] : 0.f;
            Bs[rh + i][e] = (k < DIN) ? Xb[(size_t)(j0 + e) * DIN + k] : 0.f;
        }
        __syncthreads();
        #pragma unroll
        for (int r = 0; r < 16; ++r) {
            float4 a0 = *(const float4*)&As[r][ty * 4];
            float4 a1 = *(const float4*)&As[r][64 + ty * 4];
            float4 b0 = *(const float4*)&Bs[r][tx * 4];
            float4 b1 = *(const float4*)&Bs[r][64 + tx * 4];
            float av[8] = {a0.x, a0.y, a0.z, a0.w, a1.x, a1.y, a1.z, a1.w};
            float bv[8] = {b0.x, b0.y, b0.z, b0.w, b1.x, b1.y, b1.z, b1.w};
            #pragma unroll
            for (int i = 0; i < 8; ++i)
                #pragma unroll
                for (int j = 0; j < 8; ++j)
                    acc[i][j] = fmaf(av[i], bv[j], acc[i][j]);
        }
        __syncthreads();
    }

    float sqi[8], sqj[8];
    #pragma unroll
    for (int i = 0; i < 8; ++i) {
        int ro = (i < 4) ? (ty * 4 + i) : (64 + ty * 4 + (i - 4));
        sqi[i] = SQb[i0 + ro];
    }
    #pragma unroll
    for (int j = 0; j < 8; ++j) {
        int co = (j < 4) ? (tx * 4 + j) : (64 + tx * 4 + (j - 4));
        sqj[j] = SQb[j0 + co];
    }
    #pragma unroll
    for (int i = 0; i < 8; ++i) {
        int ro = (i < 4) ? (ty * 4 + i) : (64 + ty * 4 + (i - 4));
        float* out = DTb + (size_t)(i0 + ro) * NPTS + j0;
        float4 o0, o1;
        o0.x = (sqi[i] + sqj[0]) - 2.f * acc[i][0];
        o0.y = (sqi[i] + sqj[1]) - 2.f * acc[i][1];
        o0.z = (sqi[i] + sqj[2]) - 2.f * acc[i][2];
        o0.w = (sqi[i] + sqj[3]) - 2.f * acc[i][3];
        o1.x = (sqi[i] + sqj[4]) - 2.f * acc[i][4];
        o1.y = (sqi[i] + sqj[5]) - 2.f * acc[i][5];
        o1.z = (sqi[i] + sqj[6]) - 2.f * acc[i][6];
        o1.w = (sqi[i] + sqj[7]) - 2.f * acc[i][7];
        *(float4*)(out + tx * 4) = o0;
        *(float4*)(out + 64 + tx * 4) = o1;
    }
    if (bi != bj) {
        #pragma unroll
        for (int j = 0; j < 8; ++j) {
            int co = (j < 4) ? (tx * 4 + j) : (64 + tx * 4 + (j - 4));
            float* out = DTb + (size_t)(j0 + co) * NPTS + i0;
            float4 o0, o1;
            o0.x = (sqi[0] + sqj[j]) - 2.f * acc[0][j];
            o0.y = (sqi[1] + sqj[j]) - 2.f * acc[1][j];
            o0.z = (sqi[2] + sqj[j]) - 2.f * acc[2][j];
            o0.w = (sqi[3] + sqj[j]) - 2.f * acc[3][j];
            o1.x = (sqi[4] + sqj[j]) - 2.f * acc[4][j];
            o1.y = (sqi[5] + sqj[j]) - 2.f * acc[5][j];
            o1.z = (sqi[6] + sqj[j]) - 2.f * acc[6][j];
            o1.w = (sqi[7] + sqj[j]) - 2.f * acc[7][j];
            *(float4*)(out + ty * 4) = o0;
            *(float4*)(out + 64 + ty * 4) = o1;
        }
    }
}

// ======== gram MFMA (DIN%32==0): f16x3, full 16x16 tile grid, coalesced writes ======
template <int DIN>
__global__ __launch_bounds__(256) void gram_mfma_kernel(const float* __restrict__ X,
                                                        const float* __restrict__ SQ,
                                                        float* __restrict__ DT) {
    __shared__ _Float16 Ah[128][40];
    __shared__ _Float16 Al[128][40];
    __shared__ _Float16 Bh[128][40];
    __shared__ _Float16 Bl[128][40];
    const int t = threadIdx.x;
    const int bi = blockIdx.x >> 4, bj = blockIdx.x & 15;
    const int i0 = bi * 128, j0 = bj * 128;
    const int z = blockIdx.z;
    const float* Xb = X + (size_t)z * NPTS * DIN;
    const float* SQb = SQ + (size_t)z * NPTS;
    float* DTb = DT + (size_t)z * NPTS * NPTS;

    const int e = t & 127;
    const int rh = (t >> 7) * 16;   // k-half 0 or 16
    const float* Ar = Xb + (size_t)(i0 + e) * DIN + rh;
    const float* Br = Xb + (size_t)(j0 + e) * DIN + rh;

    const int w = t >> 6;
    const int lane = t & 63;
    const int wr = (w >> 1) * 64;
    const int wc = (w & 1) * 64;
    const int lr = lane & 31;
    const int lk = (lane >> 5) * 8;
    const int hsel = lane >> 5;

    floatx16 acc[2][2];
    #pragma unroll
    for (int i = 0; i < 2; ++i)
        #pragma unroll
        for (int j = 0; j < 2; ++j)
            #pragma unroll
            for (int r = 0; r < 16; ++r) acc[i][j][r] = 0.f;

    for (int k0 = 0; k0 < DIN; k0 += 32) {
        #pragma unroll
        for (int h = 0; h < 4; ++h) {
            float4 a = *(const float4*)(Ar + k0 + h * 4);
            float4 b = *(const float4*)(Br + k0 + h * 4);
            _Float16 ah0 = (_Float16)a.x, ah1 = (_Float16)a.y, ah2 = (_Float16)a.z, ah3 = (_Float16)a.w;
            half4 av, alv;
            av.x = ah0; av.y = ah1; av.z = ah2; av.w = ah3;
            alv.x = (_Float16)(a.x - (float)ah0);
            alv.y = (_Float16)(a.y - (float)ah1);
            alv.z = (_Float16)(a.z - (float)ah2);
            alv.w = (_Float16)(a.w - (float)ah3);
            *(half4*)&Ah[e][rh + h * 4] = av;
            *(half4*)&Al[e][rh + h * 4] = alv;
            _Float16 bh0 = (_Float16)b.x, bh1 = (_Float16)b.y, bh2 = (_Float16)b.z, bh3 = (_Float16)b.w;
            half4 bv, blv;
            bv.x = bh0; bv.y = bh1; bv.z = bh2; bv.w = bh3;
            blv.x = (_Float16)(b.x - (float)bh0);
            blv.y = (_Float16)(b.y - (float)bh1);
            blv.z = (_Float16)(b.z - (float)bh2);
            blv.w = (_Float16)(b.w - (float)bh3);
            *(half4*)&Bh[e][rh + h * 4] = bv;
            *(half4*)&Bl[e][rh + h * 4] = blv;
        }
        __syncthreads();
        #pragma unroll
        for (int ks = 0; ks < 2; ++ks) {
            const int kb = ks * 16 + lk;
            half8 bf0  = *(const half8*)&Bh[wc + lr][kb];
            half8 blf0 = *(const half8*)&Bl[wc + lr][kb];
            half8 bf1  = *(const half8*)&Bh[wc + 32 + lr][kb];
            half8 blf1 = *(const half8*)&Bl[wc + 32 + lr][kb];
            #pragma unroll
            for (int i = 0; i < 2; ++i) {
                half8 af  = *(const half8*)&Ah[wr + i * 32 + lr][kb];
                half8 alf = *(const half8*)&Al[wr + i * 32 + lr][kb];
                acc[i][0] = __builtin_amdgcn_mfma_f32_32x32x16_f16(af,  bf0,  acc[i][0], 0, 0, 0);
                acc[i][0] = __builtin_amdgcn_mfma_f32_32x32x16_f16(af,  blf0, acc[i][0], 0, 0, 0);
                acc[i][0] = __builtin_amdgcn_mfma_f32_32x32x16_f16(alf, bf0,  acc[i][0], 0, 0, 0);
                acc[i][1] = __builtin_amdgcn_mfma_f32_32x32x16_f16(af,  bf1,  acc[i][1], 0, 0, 0);
                acc[i][1] = __builtin_amdgcn_mfma_f32_32x32x16_f16(af,  blf1, acc[i][1], 0, 0, 0);
                acc[i][1] = __builtin_amdgcn_mfma_f32_32x32x16_f16(alf, bf1,  acc[i][1], 0, 0, 0);
            }
        }
        __syncthreads();
    }

    const float sqj0 = SQb[j0 + wc + lr];
    const float sqj1 = SQb[j0 + wc + 32 + lr];
    #pragma unroll
    for (int i = 0; i < 2; ++i) {
        #pragma unroll
        for (int r = 0; r < 16; ++r) {
            const int row = wr + i * 32 + (r & 3) + 8 * (r >> 2) + 4 * hsel;
            const float sqi = SQb[i0 + row];
            float* out = DTb + (size_t)(i0 + row) * NPTS + j0 + wc;
            out[lr]      = (sqi + sqj0) - 2.f * acc[i][0][r];
            out[32 + lr] = (sqi + sqj1) - 2.f * acc[i][1][r];
        }
    }
}

// ---------------- knn select: one query per wave, dists in registers ----------------
__global__ __launch_bounds__(256) void knn_select_kernel(const float* __restrict__ DT,
                                                         int* __restrict__ IDX, int qoff) {
    const int t = threadIdx.x;
    const int w = t >> 6, lane = t & 63;
    const int q = blockIdx.x * 4 + w;
    const float* dq = DT + (size_t)q * NPTS;
    const int l4 = lane << 2;

    float vals[32];
    #pragma unroll
    for (int s = 0; s < 8; ++s) {
        float4 v = *(const float4*)(dq + s * 256 + l4);
        vals[s * 4 + 0] = v.x; vals[s * 4 + 1] = v.y;
        vals[s * 4 + 2] = v.z; vals[s * 4 + 3] = v.w;
    }
    unsigned rm = 0;
    float best = INFINITY; int bslot = 32;
    #pragma unroll
    for (int sl = 0; sl < 32; ++sl)
        if (vals[sl] < best) { best = vals[sl]; bslot = sl; }

    for (int rep = 0; rep < KNN; ++rep) {
        int bj = (bslot < 32) ? ((bslot >> 2) * 256 + l4 + (bslot & 3)) : NPTS;
        float gb = best; int gj = bj;
        #pragma unroll
        for (int off = 1; off < 64; off <<= 1) {
            float ov = __shfl_xor(gb, off);
            int oj = __shfl_xor(gj, off);
            if (ov < gb || (ov == gb && oj < gj)) { gb = ov; gj = oj; }
        }
        if (lane == 0) IDX[(size_t)(qoff + q) * KNN + rep] = gj;
        if (((gj >> 2) & 63) == lane) {
            int slot = ((gj >> 8) << 2) | (gj & 3);
            rm |= (1u << slot);
            best = INFINITY; bslot = 32;
            #pragma unroll
            for (int sl = 0; sl < 32; ++sl)
                if (!(rm & (1u << sl)) && vals[sl] < best) { best = vals[sl]; bslot = sl; }
        }
    }
}

// ---------------- gemm big: C[M,N] = A[M,K]@B[K,N] + bias, 128x128, BK=32, plain -----
template <int KK, int NN>
__global__ __launch_bounds__(256) void gemm_big_kernel(const float* __restrict__ A,
                                                       const float* __restrict__ B,
                                                       const float* __restrict__ bias,
                                                       float* __restrict__ C) {
    __shared__ float As[32][132];
    __shared__ float Bs[32][132];
    const int t = threadIdx.x;
    const int tx = t & 15, ty = t >> 4;
    const int m0 = blockIdx.x * 128;
    const int c0 = blockIdx.y * 128;

    float acc[8][8];
    #pragma unroll
    for (int i = 0; i < 8; ++i)
        #pragma unroll
        for (int j = 0; j < 8; ++j) acc[i][j] = 0.f;

    const int e = t & 127;
    const int rh = (t >> 7) * 16;
    const float* Ar = A + (size_t)(m0 + e) * KK + rh;
    const int br = t & 31;
    const int bc = (t >> 5) * 16;
    const float* Wbase = B + (size_t)br * NN + c0 + bc;

    for (int k0 = 0; k0 < KK; k0 += 32) {
        #pragma unroll
        for (int h = 0; h < 4; ++h) {
            float4 a = *(const float4*)(Ar + k0 + h * 4);
            As[rh + h * 4 + 0][e] = a.x; As[rh + h * 4 + 1][e] = a.y;
            As[rh + h * 4 + 2][e] = a.z; As[rh + h * 4 + 3][e] = a.w;
            *(float4*)&Bs[br][bc + h * 4] = *(const float4*)(Wbase + (size_t)k0 * NN + h * 4);
        }
        __syncthreads();
        #pragma unroll
        for (int r = 0; r < 32; ++r) {
            float4 a0 = *(const float4*)&As[r][ty * 4];
            float4 a1 = *(const float4*)&As[r][64 + ty * 4];
            float4 b0 = *(const float4*)&Bs[r][tx * 4];
            float4 b1 = *(const float4*)&Bs[r][64 + tx * 4];
            float av[8] = {a0.x, a0.y, a0.z, a0.w, a1.x, a1.y, a1.z, a1.w};
            float bv[8] = {b0.x, b0.y, b0.z, b0.w, b1.x, b1.y, b1.z, b1.w};
            #pragma unroll
            for (int i = 0; i < 8; ++i)
                #pragma unroll
                for (int j = 0; j < 8; ++j)
                    acc[i][j] = fmaf(av[i], bv[j], acc[i][j]);
        }
        __syncthreads();
    }

    float bvv[8];
    #pragma unroll
    for (int j = 0; j < 8; ++j) {
        int co = (j < 4) ? (tx * 4 + j) : (64 + tx * 4 + (j - 4));
        bvv[j] = bias[c0 + co];
    }
    #pragma unroll
    for (int i = 0; i < 8; ++i) {
        int ro = (i < 4) ? (ty * 4 + i) : (64 + ty * 4 + (i - 4));
        float* out = C + (size_t)(m0 + ro) * NN + c0;
        float4 o0, o1;
        o0.x = acc[i][0] + bvv[0]; o0.y = acc[i][1] + bvv[1];
        o0.z = acc[i][2] + bvv[2]; o0.w = acc[i][3] + bvv[3];
        o1.x = acc[i][4] + bvv[4]; o1.y = acc[i][5] + bvv[5];
        o1.z = acc[i][6] + bvv[6]; o1.w = acc[i][7] + bvv[7];
        *(float4*)(out + tx * 4) = o0;
        *(float4*)(out + 64 + tx * 4) = o1;
    }
}

// ---------------- generic tiled GEMM (fallback, 64x64): C = A@B + bias ----------------
template <int KK, int NN>
__global__ __launch_bounds__(256) void gemm_pq_kernel(const float* __restrict__ A,
                                                      const float* __restrict__ B,
                                                      const float* __restrict__ bias,
                                                      float* __restrict__ C) {
    __shared__ float As[16][68];
    __shared__ float Bs[16][64];
    const int t = threadIdx.x;
    const int tx = t & 15, ty = t >> 4;
    const int m0 = blockIdx.x * 64;
    const int c0 = blockIdx.y * 64;
    float acc[4][4];
    #pragma unroll
    for (int i = 0; i < 4; ++i)
        #pragma unroll
        for (int j = 0; j < 4; ++j) acc[i][j] = 0.f;

    constexpr int KCH = (KK + 15) / 16;
    for (int kc = 0; kc < KCH; ++kc) {
        const int k0 = kc * 16;
        {
            int m = t & 63;
            int r4 = (t >> 6) * 4;
            if constexpr (KK % 16 == 0) {
                float4 v = *(const float4*)(A + (size_t)(m0 + m) * KK + k0 + r4);
                As[r4 + 0][m] = v.x; As[r4 + 1][m] = v.y;
                As[r4 + 2][m] = v.z; As[r4 + 3][m] = v.w;
            } else {
                #pragma unroll
                for (int i = 0; i < 4; ++i) {
                    int r = r4 + i;
                    As[r][m] = (k0 + r < KK) ? A[(size_t)(m0 + m) * KK + k0 + r] : 0.f;
                }
            }
        }
        {
            int r = t >> 4;
            int c = (t & 15) * 4;
            float4 v = make_float4(0.f, 0.f, 0.f, 0.f);
            if (k0 + r < KK) v = *(const float4*)(B + (size_t)(k0 + r) * NN + c0 + c);
            *(float4*)&Bs[r][c] = v;
        }
        __syncthreads();
        #pragma unroll
        for (int r = 0; r < 16; ++r) {
            float4 a4 = *(const float4*)&As[r][ty * 4];
            float4 b4 = *(const float4*)&Bs[r][tx * 4];
            float av[4] = {a4.x, a4.y, a4.z, a4.w};
            float bv[4] = {b4.x, b4.y, b4.z, b4.w};
            #pragma unroll
            for (int i = 0; i < 4; ++i)
                #pragma unroll
                for (int j = 0; j < 4; ++j)
                    acc[i][j] = fmaf(av[i], bv[j], acc[i][j]);
        }
        __syncthreads();
    }
    float4 bv4 = *(const float4*)(bias + c0 + tx * 4);
    float bv[4] = {bv4.x, bv4.y, bv4.z, bv4.w};
    #pragma unroll
    for (int i = 0; i < 4; ++i) {
        float4 o;
        o.x = acc[i][0] + bv[0];
        o.y = acc[i][1] + bv[1];
        o.z = acc[i][2] + bv[2];
        o.w = acc[i][3] + bv[3];
        *(float4*)(C + (size_t)(m0 + ty * 4 + i) * NN + c0 + tx * 4) = o;
    }
}

// ---------------- edge small (DOUT<=32): 64 edges x 64 cols, 4x4/thread ----------
template <int D2, int DOUT>
__global__ __launch_bounds__(256) void edge_kernel(const float* __restrict__ PQ,
                                                   const int* __restrict__ IDX,
                                                   const float* __restrict__ W2,
                                                   const float* __restrict__ b2,
                                                   float* __restrict__ Xn) {
    constexpr int N4 = 2 * D2;
    __shared__ float As[16][68];
    __shared__ float Bs[16][64];
    __shared__ int gjs[64];
    const int t = threadIdx.x;
    const int tx = t & 15, ty = t >> 4;
    const int nb = blockIdx.x * 4;
    const int c0 = blockIdx.y * 64;

    if (t < 64) {
        int node = nb + (t >> 4);
        int bstart = (node / NPTS) * NPTS;
        gjs[t] = bstart + IDX[(size_t)node * KNN + (t & 15)];
    }
    __syncthreads();

    float acc[4][4];
    #pragma unroll
    for (int i = 0; i < 4; ++i)
        #pragma unroll
        for (int j = 0; j < 4; ++j) acc[i][j] = 0.f;

    const int e = t & 63;
    const int r4 = (t >> 6) * 4;
    const int gi = nb + (e >> 4);

    for (int k0 = 0; k0 < D2; k0 += 16) {
        {
            int gj = gjs[e];
            float4 p = *(const float4*)(PQ + (size_t)gi * N4 + k0 + r4);
            float4 q = *(const float4*)(PQ + (size_t)gj * N4 + D2 + k0 + r4);
            As[r4 + 0][e] = fmaxf(p.x + q.x, 0.f);
            As[r4 + 1][e] = fmaxf(p.y + q.y, 0.f);
            As[r4 + 2][e] = fmaxf(p.z + q.z, 0.f);
            As[r4 + 3][e] = fmaxf(p.w + q.w, 0.f);
        }
        {
            int r = t >> 4;
            int c = (t & 15) * 4;
            float4 v = make_float4(0.f, 0.f, 0.f, 0.f);
            if (c0 + c < DOUT) v = *(const float4*)(W2 + (size_t)(k0 + r) * DOUT + c0 + c);
            *(float4*)&Bs[r][c] = v;
        }
        __syncthreads();
        #pragma unroll
        for (int r = 0; r < 16; ++r) {
            float4 a4 = *(const float4*)&As[r][ty * 4];
            float4 b4 = *(const float4*)&Bs[r][tx * 4];
            float av[4] = {a4.x, a4.y, a4.z, a4.w};
            float bv[4] = {b4.x, b4.y, b4.z, b4.w};
            #pragma unroll
            for (int i = 0; i < 4; ++i)
                #pragma unroll
                for (int j = 0; j < 4; ++j)
                    acc[i][j] = fmaf(av[i], bv[j], acc[i][j]);
        }
        __syncthreads();
    }

    float bv[4];
    #pragma unroll
    for (int j = 0; j < 4; ++j) {
        int c = c0 + tx * 4 + j;
        bv[j] = (c < DOUT) ? b2[c] : 0.f;
    }
    float s[4];
    #pragma unroll
    for (int j = 0; j < 4; ++j) {
        float ss = 0.f;
        #pragma unroll
        for (int i = 0; i < 4; ++i) ss += fmaxf(acc[i][j] + bv[j], 0.f);
        s[j] = ss;
    }
    #pragma unroll
    for (int j = 0; j < 4; ++j) Bs[ty][tx * 4 + j] = s[j];
    __syncthreads();
    if ((ty & 3) == 0) {
        int node = nb + (ty >> 2);
        #pragma unroll
        for (int j = 0; j < 4; ++j) {
            int c = c0 + tx * 4 + j;
            if (c < DOUT) {
                int cc = tx * 4 + j;
                float tot = Bs[ty][cc] + Bs[ty + 1][cc] + Bs[ty + 2][cc] + Bs[ty + 3][cc];
                Xn[(size_t)node * DOUT + c] = tot * (1.f / 16.f);
            }
        }
    }
}

// ======== edge big (DOUT>=128): f16x3 MFMA, A+B LDS DOUBLE-BUFFER, 1 barrier/K-step ==
// (round-8 proven best: 311us; + s_setprio around MFMA cluster, guarded tail prefetch)
#define EBG_LOAD(KN)                                                                 \
  { _Pragma("unroll")                                                                \
    for (int h = 0; h < 4; ++h) {                                                    \
      pp[h] = *(const float4*)(Prow + (KN) + rh + h * 4);                            \
      qq[h] = *(const float4*)(Qrow + (KN) + rh + h * 4);                            \
    }                                                                                \
    wh = *(const half8*)(WHrow + (KN));                                              \
    wl = *(const half8*)(WLrow + (KN)); }

#define EBG_STAGE(dst)                                                               \
  { _Pragma("unroll")                                                                \
    for (int h = 0; h < 4; ++h) {                                                    \
      float a0 = fmaxf(pp[h].x + qq[h].x, 0.f);                                      \
      float a1 = fmaxf(pp[h].y + qq[h].y, 0.f);                                      \
      float a2 = fmaxf(pp[h].z + qq[h].z, 0.f);                                      \
      float a3 = fmaxf(pp[h].w + qq[h].w, 0.f);                                      \
      _Float16 h0 = (_Float16)a0, h1 = (_Float16)a1;                                 \
      _Float16 h2 = (_Float16)a2, h3 = (_Float16)a3;                                 \
      half4 hv, lv;                                                                  \
      hv.x = h0; hv.y = h1; hv.z = h2; hv.w = h3;                                    \
      lv.x = (_Float16)(a0 - (float)h0);                                             \
      lv.y = (_Float16)(a1 - (float)h1);                                             \
      lv.z = (_Float16)(a2 - (float)h2);                                             \
      lv.w = (_Float16)(a3 - (float)h3);                                             \
      *(half4*)&Ah[dst][e][rh + h * 4] = hv;                                         \
      *(half4*)&Al[dst][e][rh + h * 4] = lv;                                         \
    }                                                                                \
    *(half8*)&Bh[dst][eb][rb] = wh;                                                  \
    *(half8*)&Bl[dst][eb][rb] = wl; }

#define EBG_MFMA(cur)                                                                \
  { __builtin_amdgcn_s_setprio(1);                                                   \
    _Pragma("unroll")                                                                \
    for (int ks = 0; ks < 2; ++ks) {                                                 \
      const int kb = ks * 16 + lk;                                                   \
      half8 bf0  = *(const half8*)&Bh[cur][wc + lr][kb];                             \
      half8 blf0 = *(const half8*)&Bl[cur][wc + lr][kb];                             \
      half8 bf1  = *(const half8*)&Bh[cur][wc + 32 + lr][kb];                        \
      half8 blf1 = *(const half8*)&Bl[cur][wc + 32 + lr][kb];                        \
      _Pragma("unroll")                                                              \
      for (int i = 0; i < 2; ++i) {                                                  \
        half8 af  = *(const half8*)&Ah[cur][wr + i * 32 + lr][kb];                   \
        half8 alf = *(const half8*)&Al[cur][wr + i * 32 + lr][kb];                   \
        acc[i][0] = __builtin_amdgcn_mfma_f32_32x32x16_f16(af,  bf0,  acc[i][0], 0, 0, 0); \
        acc[i][0] = __builtin_amdgcn_mfma_f32_32x32x16_f16(af,  blf0, acc[i][0], 0, 0, 0); \
        acc[i][0] = __builtin_amdgcn_mfma_f32_32x32x16_f16(alf, bf0,  acc[i][0], 0, 0, 0); \
        acc[i][1] = __builtin_amdgcn_mfma_f32_32x32x16_f16(af,  bf1,  acc[i][1], 0, 0, 0); \
        acc[i][1] = __builtin_amdgcn_mfma_f32_32x32x16_f16(af,  blf1, acc[i][1], 0, 0, 0); \
        acc[i][1] = __builtin_amdgcn_mfma_f32_32x32x16_f16(alf, bf1,  acc[i][1], 0, 0, 0); \
      }                                                                              \
    }                                                                                \
    __builtin_amdgcn_s_setprio(0); }

template <int D2, int DOUT>
__global__ __launch_bounds__(512) void edge_big_mfma_kernel(const float* __restrict__ PQ,
                                                            const int* __restrict__ IDX,
                                                            const _Float16* __restrict__ W2H,
                                                            const _Float16* __restrict__ W2L,
                                                            const float* __restrict__ b2,
                                                            float* __restrict__ Xn) {
    constexpr int N4 = 2 * D2;
    constexpr int NSTEP = D2 / 32;
    __shared__ _Float16 Ah[2][256][40];
    __shared__ _Float16 Al[2][256][40];
    __shared__ _Float16 Bh[2][128][40];
    __shared__ _Float16 Bl[2][128][40];
    __shared__ int gjs[256];
    const int t = threadIdx.x;
    const int nb16 = blockIdx.x * 16;
    const int c0 = blockIdx.y * 128;

    if (t < 256) {
        int node = nb16 + (t >> 4);
        int bstart = (node / NPTS) * NPTS;
        gjs[t] = bstart + IDX[(size_t)node * KNN + (t & 15)];
    }
    __syncthreads();

    const int e  = t & 255;
    const int rh = (t >> 8) * 16;
    const int gi = nb16 + (e >> 4);
    const int gj = gjs[e];
    const float* Prow = PQ + (size_t)gi * N4;
    const float* Qrow = PQ + (size_t)gj * N4 + D2;
    const int eb = t & 127;
    const int rb = (t >> 7) * 8;
    const _Float16* WHrow = W2H + (size_t)(c0 + eb) * D2 + rb;
    const _Float16* WLrow = W2L + (size_t)(c0 + eb) * D2 + rb;

    const int w = t >> 6;
    const int lane = t & 63;
    const int wr = (w >> 1) * 64;
    const int wc = (w & 1) * 64;
    const int lr = lane & 31;
    const int lk = (lane >> 5) * 8;
    const int hsel = lane >> 5;

    floatx16 acc[2][2];
    #pragma unroll
    for (int i = 0; i < 2; ++i)
        #pragma unroll
        for (int j = 0; j < 2; ++j)
            #pragma unroll
            for (int r = 0; r < 16; ++r) acc[i][j][r] = 0.f;

    float4 pp[4], qq[4];
    half8 wh, wl;

    EBG_LOAD(0)
    EBG_STAGE(0)
    EBG_LOAD(32)
    asm volatile("s_waitcnt lgkmcnt(0)" ::: "memory");
    __builtin_amdgcn_s_barrier();
    asm volatile("" ::: "memory");

    for (int s = 0; s < NSTEP - 1; ++s) {
        const int cur = s & 1;
        EBG_MFMA(cur)
        EBG_STAGE(cur ^ 1)
        if (s + 2 < NSTEP) EBG_LOAD((s + 2) * 32)
        asm volatile("s_waitcnt lgkmcnt(0)" ::: "memory");
        __builtin_amdgcn_s_barrier();
        asm volatile("" ::: "memory");
    }
    EBG_MFMA((NSTEP - 1) & 1)

    float bb[2];
    bb[0] = b2[c0 + wc + lr];
    bb[1] = b2[c0 + wc + 32 + lr];
    #pragma unroll
    for (int i = 0; i < 2; ++i) {
        int node0 = nb16 + ((wr + i * 32) >> 4);
        #pragma unroll
        for (int j = 0; j < 2; ++j) {
            float sA = 0.f, sB = 0.f;
            #pragma unroll
            for (int r = 0; r < 8; ++r)  sA += fmaxf(acc[i][j][r] + bb[j], 0.f);
            #pragma unroll
            for (int r = 8; r < 16; ++r) sB += fmaxf(acc[i][j][r] + bb[j], 0.f);
            sA += __shfl_xor(sA, 32);
            sB += __shfl_xor(sB, 32);
            if (hsel == 0) {
                int col = c0 + wc + j * 32 + lr;
                Xn[(size_t)node0 * DOUT + col] = sA * (1.f / 16.f);
                Xn[(size_t)(node0 + 1) * DOUT + col] = sB * (1.f / 16.f);
            }
        }
    }
}
#undef EBG_LOAD
#undef EBG_STAGE
#undef EBG_MFMA

// ======== edge mid (DOUT==64): f16x3 MFMA, round-4 depth-2 pipeline, 64x32/wave =====
// (31 KB LDS -> 5 blocks/CU; round-10 proved occupancy beats dbuf depth here)
#define EM_STAGE_MFMA(KC, QQ, POK, KP)                                               \
  {                                                                                  \
    half8 wh0 = *(const half8*)(WHrow + (KC));                                       \
    half8 wl0 = *(const half8*)(WLrow + (KC));                                       \
    _Pragma("unroll")                                                                \
    for (int h = 0; h < 4; ++h) {                                                    \
      float4 p = *(const float4*)(Prow + (KC) + rh + h * 4);                         \
      float a0 = fmaxf(p.x + QQ[h].x, 0.f);                                          \
      float a1 = fmaxf(p.y + QQ[h].y, 0.f);                                          \
      float a2 = fmaxf(p.z + QQ[h].z, 0.f);                                          \
      float a3 = fmaxf(p.w + QQ[h].w, 0.f);                                          \
      _Float16 h0 = (_Float16)a0, h1 = (_Float16)a1;                                 \
      _Float16 h2 = (_Float16)a2, h3 = (_Float16)a3;                                 \
      half4 hv, lv;                                                                  \
      hv.x = h0; hv.y = h1; hv.z = h2; hv.w = h3;                                    \
      lv.x = (_Float16)(a0 - (float)h0);                                             \
      lv.y = (_Float16)(a1 - (float)h1);                                             \
      lv.z = (_Float16)(a2 - (float)h2);                                             \
      lv.w = (_Float16)(a3 - (float)h3);                                             \
      *(half4*)&Ah[e][rh + h * 4] = hv;                                              \
      *(half4*)&Al[e][rh + h * 4] = lv;                                              \
    }                                                                                \
    *(half8*)&Bh[wrB][wkB] = wh0;                                                    \
    *(half8*)&Bl[wrB][wkB] = wl0;                                                    \
    if (POK) {                                                                       \
      _Pragma("unroll")                                                              \
      for (int h = 0; h < 4; ++h)                                                    \
        QQ[h] = *(const float4*)(Qrow + (KP) + rh + h * 4);                          \
    }                                                                                \
    asm volatile("s_waitcnt lgkmcnt(0)" ::: "memory");                               \
    __builtin_amdgcn_s_barrier();                                                    \
    asm volatile("" ::: "memory");                                                   \
    _Pragma("unroll")                                                                \
    for (int ks = 0; ks < 2; ++ks) {                                                 \
      const int kb = ks * 16 + lk;                                                   \
      half8 bf0 = *(const half8*)&Bh[wc + lr][kb];                                   \
      half8 blf0 = *(const half8*)&Bl[wc + lr][kb];                                  \
      _Pragma("unroll")                                                              \
      for (int i = 0; i < 2; ++i) {                                                  \
        half8 af = *(const half8*)&Ah[wr + i * 32 + lr][kb];                         \
        half8 alf = *(const half8*)&Al[wr + i * 32 + lr][kb];                        \
        acc[i] = __builtin_amdgcn_mfma_f32_32x32x16_f16(af, bf0, acc[i], 0, 0, 0);   \
        acc[i] = __builtin_amdgcn_mfma_f32_32x32x16_f16(af, blf0, acc[i], 0, 0, 0);  \
        acc[i] = __builtin_amdgcn_mfma_f32_32x32x16_f16(alf, bf0, acc[i], 0, 0, 0);  \
      }                                                                              \
    }                                                                                \
    asm volatile("" ::: "memory");                                                   \
    __builtin_amdgcn_s_barrier();                                                    \
    asm volatile("" ::: "memory");                                                   \
  }

template <int D2, int DOUT>
__global__ __launch_bounds__(256) void edge_mid_mfma_kernel(const float* __restrict__ PQ,
                                                            const int* __restrict__ IDX,
                                                            const _Float16* __restrict__ W2H,
                                                            const _Float16* __restrict__ W2L,
                                                            const float* __restrict__ b2,
                                                            float* __restrict__ Xn) {
    constexpr int N4 = 2 * D2;
    __shared__ _Float16 Ah[128][40];
    __shared__ _Float16 Al[128][40];
    __shared__ _Float16 Bh[64][40];
    __shared__ _Float16 Bl[64][40];
    __shared__ int gjs[128];
    const int t = threadIdx.x;
    const int nb8 = blockIdx.x * 8;

    if (t < 128) {
        int node = nb8 + (t >> 4);
        int bstart = (node / NPTS) * NPTS;
        gjs[t] = bstart + IDX[(size_t)node * KNN + (t & 15)];
    }
    __syncthreads();

    const int e = t & 127;
    const int rh = (t >> 7) * 16;
    const int gi = nb8 + (e >> 4);
    const int gj = gjs[e];
    const float* Prow = PQ + (size_t)gi * N4;
    const float* Qrow = PQ + (size_t)gj * N4 + D2;
    const int wrB = t & 63;
    const int wkB = (t >> 6) * 8;
    const _Float16* WHrow = W2H + (size_t)wrB * D2 + wkB;
    const _Float16* WLrow = W2L + (size_t)wrB * D2 + wkB;

    const int w = t >> 6;
    const int lane = t & 63;
    const int wr = (w >> 1) * 64;
    const int wc = (w & 1) * 32;
    const int lr = lane & 31;
    const int lk = (lane >> 5) * 8;
    const int hsel = lane >> 5;

    floatx16 acc[2];
    #pragma unroll
    for (int i = 0; i < 2; ++i)
        #pragma unroll
        for (int r = 0; r < 16; ++r) acc[i][r] = 0.f;

    float4 qqA[4], qqB[4];
    #pragma unroll
    for (int h = 0; h < 4; ++h) qqA[h] = *(const float4*)(Qrow + rh + h * 4);
    #pragma unroll
    for (int h = 0; h < 4; ++h) qqB[h] = *(const float4*)(Qrow + 32 + rh + h * 4);

    for (int k0 = 0; k0 < D2; k0 += 64) {
        EM_STAGE_MFMA(k0,      qqA, (k0 + 64 < D2), k0 + 64)
        EM_STAGE_MFMA(k0 + 32, qqB, (k0 + 96 < D2), k0 + 96)
    }

    float bb = b2[wc + lr];
    #pragma unroll
    for (int i = 0; i < 2; ++i) {
        int node0 = nb8 + ((wr + i * 32) >> 4);
        float sA = 0.f, sB = 0.f;
        #pragma unroll
        for (int r = 0; r < 8; ++r)  sA += fmaxf(acc[i][r] + bb, 0.f);
        #pragma unroll
        for (int r = 8; r < 16; ++r) sB += fmaxf(acc[i][r] + bb, 0.f);
        sA += __shfl_xor(sA, 32);
        sB += __shfl_xor(sB, 32);
        if (hsel == 0) {
            int col = wc + lr;
            Xn[(size_t)node0 * DOUT + col] = sA * (1.f / 16.f);
            Xn[(size_t)(node0 + 1) * DOUT + col] = sB * (1.f / 16.f);
        }
    }
}
#undef EM_STAGE_MFMA

// ---------------- final: mean over nodes + 16x2 projection ----------------
__global__ __launch_bounds__(256) void final_kernel(const float* __restrict__ X,
                                                    const float* __restrict__ Wf,
                                                    const float* __restrict__ bfin,
                                                    float* __restrict__ out) {
    __shared__ float red[16][17];
    __shared__ float pool[16];
    const int b = blockIdx.x;
    const int t = threadIdx.x;
    const int c = t & 15, rg = t >> 4;
    float s = 0.f;
    for (int n = rg; n < NPTS; n += 16) s += X[(size_t)(b * NPTS + n) * 16 + c];
    red[rg][c] = s;
    __syncthreads();
    if (t < 16) {
        float tot = 0.f;
        #pragma unroll
        for (int i = 0; i < 16; ++i) tot += red[i][t];
        pool[t] = tot * (1.f / NPTS);
    }
    __syncthreads();
    if (t < 2) {
        float a = bfin[t];
        #pragma unroll
        for (int cc = 0; cc < 16; ++cc) a = fmaf(pool[cc], Wf[cc * 2 + t], a);
        out[b * 2 + t] = a;
    }
}

// ---------------- per-layer driver ----------------
template <int DIN, int DOUT>
static void run_layer(const float* Xin, float* Xout, float* PQ, float* SQ, int* IDX,
                      float* WCAT, float* BCAT, _Float16* W2H, _Float16* W2L,
                      const float* W1, const float* b1, const float* W2, const float* b2,
                      hipStream_t stream) {
    constexpr int D2 = 2 * DOUT;
    constexpr int N4 = 2 * D2;
    constexpr int prep_blocks = (DIN * N4 + 255) / 256;
    constexpr int w2_blocks = (DOUT >= 64) ? ((D2 * DOUT + 255) / 256) : 0;
    sqprep_kernel<<<BN / 256 + prep_blocks + w2_blocks, 256, 0, stream>>>(
        Xin, SQ, W1, b1, WCAT, BCAT, DIN, D2, W2, W2H, W2L,
        (DOUT >= 64) ? DOUT : 0, prep_blocks);
    for (int h = 0; h < 2; ++h) {
        if constexpr (DIN % 32 == 0) {
            dim3 gg(256, 1, 4);   // full 16x16 tile grid, coalesced writes
            gram_mfma_kernel<DIN><<<gg, 256, 0, stream>>>(Xin + (size_t)h * 4 * NPTS * DIN,
                                                          SQ + (size_t)h * 4 * NPTS, PQ);
        } else {
            dim3 gg(136, 1, 4);   // triangular fp32 path (DIN=3)
            gram_kernel<DIN><<<gg, 256, 0, stream>>>(Xin + (size_t)h * 4 * NPTS * DIN,
                                                     SQ + (size_t)h * 4 * NPTS, PQ);
        }
        knn_select_kernel<<<2048, 256, 0, stream>>>(PQ, IDX, h * 8192);
    }
    if constexpr (N4 % 128 == 0 && DIN % 32 == 0) {
        dim3 g1(BN / 128, N4 / 128);
        gemm_big_kernel<DIN, N4><<<g1, 256, 0, stream>>>(Xin, WCAT, BCAT, PQ);
    } else {
        dim3 g1(BN / 64, N4 / 64);
        gemm_pq_kernel<DIN, N4><<<g1, 256, 0, stream>>>(Xin, WCAT, BCAT, PQ);
    }
    if constexpr (DOUT >= 128) {
        dim3 g2(BN / 16, DOUT / 128);
        edge_big_mfma_kernel<D2, DOUT><<<g2, 512, 0, stream>>>(PQ, IDX, W2H, W2L, b2, Xout);
    } else if constexpr (DOUT == 64) {
        dim3 g2(BN / 8, 1);
        edge_mid_mfma_kernel<D2, DOUT><<<g2, 256, 0, stream>>>(PQ, IDX, W2H, W2L, b2, Xout);
    } else {
        dim3 g2(BN / 4, (DOUT + 63) / 64);
        edge_kernel<D2, DOUT><<<g2, 256, 0, stream>>>(PQ, IDX, W2, b2, Xout);
    }
}

extern "C" void kernel_launch(void* const* d_in, const int* in_sizes, int n_in,
                              void* d_out, int out_size, void* d_ws, size_t ws_size,
                              hipStream_t stream) {
    (void)in_sizes; (void)n_in; (void)out_size; (void)ws_size;
    const float* x = (const float*)d_in[0];
    const float* W1a[6]; const float* b1a[6]; const float* W2a[6]; const float* b2a[6];
    for (int l = 0; l < 6; ++l) {
        W1a[l] = (const float*)d_in[1 + 4 * l];
        b1a[l] = (const float*)d_in[2 + 4 * l];
        W2a[l] = (const float*)d_in[3 + 4 * l];
        b2a[l] = (const float*)d_in[4 + 4 * l];
    }
    const float* Wf = (const float*)d_in[25];
    const float* bfin = (const float*)d_in[26];

    float* ws = (float*)d_ws;
    float* X0   = ws;                                   // 16384*256
    float* X1   = X0 + (size_t)BN * 256;                // 16384*256
    float* PQ   = X1 + (size_t)BN * 256;                // 16384*1024 (also knn DT)
    float* SQ   = PQ + (size_t)BN * 1024;               // 16384
    int*   IDX  = (int*)(SQ + BN);                      // 16384*16
    float* WCAT = (float*)(IDX + (size_t)BN * KNN);     // 131072
    float* BCAT = WCAT + 131072;                        // 1024
    _Float16* W2H = (_Float16*)(BCAT + 1024);           // 131072 halfs (256 KB)
    _Float16* W2L = W2H + 131072;                       // 131072 halfs (256 KB)

    run_layer<3,   32>(x,  X0, PQ, SQ, IDX, WCAT, BCAT, W2H, W2L, W1a[0], b1a[0], W2a[0], b2a[0], stream);
    run_layer<32, 128>(X0, X1, PQ, SQ, IDX, WCAT, BCAT, W2H, W2L, W1a[1], b1a[1], W2a[1], b2a[1], stream);
    run_layer<128,256>(X1, X0, PQ, SQ, IDX, WCAT, BCAT, W2H, W2L, W1a[2], b1a[2], W2a[2], b2a[2], stream);
    run_layer<256, 64>(X0, X1, PQ, SQ, IDX, WCAT, BCAT, W2H, W2L, W1a[3], b1a[3], W2a[3], b2a[3], stream);
    run_layer<64,  32>(X1, X0, PQ, SQ, IDX, WCAT, BCAT, W2H, W2L, W1a[4], b1a[4], W2a[4], b2a[4], stream);
    run_layer<32,  16>(X0, X1, PQ, SQ, IDX, WCAT, BCAT, W2H, W2L, W1a[5], b1a[5], W2a[5], b2a[5], stream);
    final_kernel<<<NB, 256, 0, stream>>>(X1, Wf, bfin, (float*)d_out);
}

// Round 13
// 1723.352 us; speedup vs baseline: 1.0789x; 1.0382x over previous
//
#include <hip/hip_runtime.h>
#include <math.h>

#define NPTS 2048
#define NB 8
#define BN 16384   // NB*NPTS
#define KNN 16

typedef _Float16 half4 __attribute__((ext_vector_type(4)));
typedef _Float16 half8 __attribute__((ext_vector_type(8)));
typedef float floatx16 __attribute__((ext_vector_type(16)));

// ---------------- fused sq + prep: sq | Wcat/bcat | W2 hi/lo split (transposed) ------
__global__ __launch_bounds__(256) void sqprep_kernel(const float* __restrict__ X,
                                                     float* __restrict__ SQ,
                                                     const float* __restrict__ W1,
                                                     const float* __restrict__ b1,
                                                     float* __restrict__ Wcat,
                                                     float* __restrict__ bcat,
                                                     int din, int d2,
                                                     const float* __restrict__ W2,
                                                     _Float16* __restrict__ W2H,
                                                     _Float16* __restrict__ W2L,
                                                     int dout, int pb) {
    const int bid = blockIdx.x;
    if (bid < BN / 256) {
        int g = bid * 256 + threadIdx.x;
        const float* row = X + (size_t)g * din;
        float s = 0.f;
        for (int d = 0; d < din; ++d) s = fmaf(row[d], row[d], s);
        SQ[g] = s;
    } else if (bid < BN / 256 + pb) {
        int n4 = 2 * d2;
        int total = din * n4;
        int i = (bid - BN / 256) * 256 + threadIdx.x;
        if (i < total) {
            int d = i / n4, c = i - d * n4;
            float v;
            if (c < d2) v = W1[d * d2 + c] - W1[(din + d) * d2 + c];
            else        v = W1[(din + d) * d2 + (c - d2)];
            Wcat[i] = v;
        }
        if (i < n4) bcat[i] = (i < d2) ? b1[i] : 0.f;
    } else {
        // W2 split: W2 is [d2][dout] fp32 -> W2H/W2L [dout][d2] f16 (hi + residual lo)
        int i = (bid - BN / 256 - pb) * 256 + threadIdx.x;
        if (i < d2 * dout) {
            int k = i / dout, c = i - k * dout;
            float wv = W2[i];
            _Float16 hv = (_Float16)wv;
            float rv = wv - (float)hv;
            W2H[(size_t)c * d2 + k] = hv;
            W2L[(size_t)c * d2 + k] = (_Float16)rv;
        }
    }
}

// ---------------- gram fp32 (DIN=3 only): triangular tile grid, mirror write ---------
template <int DIN>
__global__ __launch_bounds__(256) void gram_kernel(const float* __restrict__ X,
                                                   const float* __restrict__ SQ,
                                                   float* __restrict__ DT) {
    __shared__ float As[32][132];
    __shared__ float Bs[32][132];
    const int t = threadIdx.x;
    const int tx = t & 15, ty = t >> 4;
    int bid = blockIdx.x;
    int bi = 0;
    while (bid >= 16 - bi) { bid -= 16 - bi; ++bi; }
    const int bj = bi + bid;
    const int i0 = bi * 128;
    const int j0 = bj * 128;
    const int z = blockIdx.z;
    const float* Xb = X + (size_t)z * NPTS * DIN;
    const float* SQb = SQ + (size_t)z * NPTS;
    float* DTb = DT + (size_t)z * NPTS * NPTS;

    const int e = t & 127;

    float acc[8][8];
    #pragma unroll
    for (int i = 0; i < 8; ++i)
        #pragma unroll
        for (int j = 0; j < 8; ++j) acc[i][j] = 0.f;

    {
        const int rh = (t >> 7) * 8;
        #pragma unroll
        for (int i = 0; i < 8; ++i) {
            int k = rh + i;
            As[rh + i][e] = (k < DIN) ? Xb[(size_t)(i0 + e) * DIN + k] : 0.f;
            Bs[rh + i][e] = (k < DIN) ? Xb[(size_t)(j0 + e) * DIN + k] : 0.f;
        }
        __syncthreads();
        #pragma unroll
        for (int r = 0; r < 16; ++r) {
            float4 a0 = *(const float4*)&As[r][ty * 4];
            float4 a1 = *(const float4*)&As[r][64 + ty * 4];
            float4 b0 = *(const float4*)&Bs[r][tx * 4];
            float4 b1 = *(const float4*)&Bs[r][64 + tx * 4];
            float av[8] = {a0.x, a0.y, a0.z, a0.w, a1.x, a1.y, a1.z, a1.w};
            float bv[8] = {b0.x, b0.y, b0.z, b0.w, b1.x, b1.y, b1.z, b1.w};
            #pragma unroll
            for (int i = 0; i < 8; ++i)
                #pragma unroll
                for (int j = 0; j < 8; ++j)
                    acc[i][j] = fmaf(av[i], bv[j], acc[i][j]);
        }
        __syncthreads();
    }

    float sqi[8], sqj[8];
    #pragma unroll
    for (int i = 0; i < 8; ++i) {
        int ro = (i < 4) ? (ty * 4 + i) : (64 + ty * 4 + (i - 4));
        sqi[i] = SQb[i0 + ro];
    }
    #pragma unroll
    for (int j = 0; j < 8; ++j) {
        int co = (j < 4) ? (tx * 4 + j) : (64 + tx * 4 + (j - 4));
        sqj[j] = SQb[j0 + co];
    }
    #pragma unroll
    for (int i = 0; i < 8; ++i) {
        int ro = (i < 4) ? (ty * 4 + i) : (64 + ty * 4 + (i - 4));
        float* out = DTb + (size_t)(i0 + ro) * NPTS + j0;
        float4 o0, o1;
        o0.x = (sqi[i] + sqj[0]) - 2.f * acc[i][0];
        o0.y = (sqi[i] + sqj[1]) - 2.f * acc[i][1];
        o0.z = (sqi[i] + sqj[2]) - 2.f * acc[i][2];
        o0.w = (sqi[i] + sqj[3]) - 2.f * acc[i][3];
        o1.x = (sqi[i] + sqj[4]) - 2.f * acc[i][4];
        o1.y = (sqi[i] + sqj[5]) - 2.f * acc[i][5];
        o1.z = (sqi[i] + sqj[6]) - 2.f * acc[i][6];
        o1.w = (sqi[i] + sqj[7]) - 2.f * acc[i][7];
        *(float4*)(out + tx * 4) = o0;
        *(float4*)(out + 64 + tx * 4) = o1;
    }
    if (bi != bj) {
        #pragma unroll
        for (int j = 0; j < 8; ++j) {
            int co = (j < 4) ? (tx * 4 + j) : (64 + tx * 4 + (j - 4));
            float* out = DTb + (size_t)(j0 + co) * NPTS + i0;
            float4 o0, o1;
            o0.x = (sqi[0] + sqj[j]) - 2.f * acc[0][j];
            o0.y = (sqi[1] + sqj[j]) - 2.f * acc[1][j];
            o0.z = (sqi[2] + sqj[j]) - 2.f * acc[2][j];
            o0.w = (sqi[3] + sqj[j]) - 2.f * acc[3][j];
            o1.x = (sqi[4] + sqj[j]) - 2.f * acc[4][j];
            o1.y = (sqi[5] + sqj[j]) - 2.f * acc[5][j];
            o1.z = (sqi[6] + sqj[j]) - 2.f * acc[6][j];
            o1.w = (sqi[7] + sqj[j]) - 2.f * acc[7][j];
            *(float4*)(out + ty * 4) = o0;
            *(float4*)(out + 64 + ty * 4) = o1;
        }
    }
}

// ======== gram MFMA (DIN%32==0): f16x3, full 16x16 tile grid, coalesced writes ======
template <int DIN>
__global__ __launch_bounds__(256) void gram_mfma_kernel(const float* __restrict__ X,
                                                        const float* __restrict__ SQ,
                                                        float* __restrict__ DT) {
    __shared__ _Float16 Ah[128][40];
    __shared__ _Float16 Al[128][40];
    __shared__ _Float16 Bh[128][40];
    __shared__ _Float16 Bl[128][40];
    const int t = threadIdx.x;
    const int bi = blockIdx.x >> 4, bj = blockIdx.x & 15;
    const int i0 = bi * 128, j0 = bj * 128;
    const int z = blockIdx.z;
    const float* Xb = X + (size_t)z * NPTS * DIN;
    const float* SQb = SQ + (size_t)z * NPTS;
    float* DTb = DT + (size_t)z * NPTS * NPTS;

    const int e = t & 127;
    const int rh = (t >> 7) * 16;   // k-half 0 or 16
    const float* Ar = Xb + (size_t)(i0 + e) * DIN + rh;
    const float* Br = Xb + (size_t)(j0 + e) * DIN + rh;

    const int w = t >> 6;
    const int lane = t & 63;
    const int wr = (w >> 1) * 64;
    const int wc = (w & 1) * 64;
    const int lr = lane & 31;
    const int lk = (lane >> 5) * 8;
    const int hsel = lane >> 5;

    floatx16 acc[2][2];
    #pragma unroll
    for (int i = 0; i < 2; ++i)
        #pragma unroll
        for (int j = 0; j < 2; ++j)
            #pragma unroll
            for (int r = 0; r < 16; ++r) acc[i][j][r] = 0.f;

    for (int k0 = 0; k0 < DIN; k0 += 32) {
        #pragma unroll
        for (int h = 0; h < 4; ++h) {
            float4 a = *(const float4*)(Ar + k0 + h * 4);
            float4 b = *(const float4*)(Br + k0 + h * 4);
            _Float16 ah0 = (_Float16)a.x, ah1 = (_Float16)a.y, ah2 = (_Float16)a.z, ah3 = (_Float16)a.w;
            half4 av, alv;
            av.x = ah0; av.y = ah1; av.z = ah2; av.w = ah3;
            alv.x = (_Float16)(a.x - (float)ah0);
            alv.y = (_Float16)(a.y - (float)ah1);
            alv.z = (_Float16)(a.z - (float)ah2);
            alv.w = (_Float16)(a.w - (float)ah3);
            *(half4*)&Ah[e][rh + h * 4] = av;
            *(half4*)&Al[e][rh + h * 4] = alv;
            _Float16 bh0 = (_Float16)b.x, bh1 = (_Float16)b.y, bh2 = (_Float16)b.z, bh3 = (_Float16)b.w;
            half4 bv, blv;
            bv.x = bh0; bv.y = bh1; bv.z = bh2; bv.w = bh3;
            blv.x = (_Float16)(b.x - (float)bh0);
            blv.y = (_Float16)(b.y - (float)bh1);
            blv.z = (_Float16)(b.z - (float)bh2);
            blv.w = (_Float16)(b.w - (float)bh3);
            *(half4*)&Bh[e][rh + h * 4] = bv;
            *(half4*)&Bl[e][rh + h * 4] = blv;
        }
        __syncthreads();
        #pragma unroll
        for (int ks = 0; ks < 2; ++ks) {
            const int kb = ks * 16 + lk;
            half8 bf0  = *(const half8*)&Bh[wc + lr][kb];
            half8 blf0 = *(const half8*)&Bl[wc + lr][kb];
            half8 bf1  = *(const half8*)&Bh[wc + 32 + lr][kb];
            half8 blf1 = *(const half8*)&Bl[wc + 32 + lr][kb];
            #pragma unroll
            for (int i = 0; i < 2; ++i) {
                half8 af  = *(const half8*)&Ah[wr + i * 32 + lr][kb];
                half8 alf = *(const half8*)&Al[wr + i * 32 + lr][kb];
                acc[i][0] = __builtin_amdgcn_mfma_f32_32x32x16_f16(af,  bf0,  acc[i][0], 0, 0, 0);
                acc[i][0] = __builtin_amdgcn_mfma_f32_32x32x16_f16(af,  blf0, acc[i][0], 0, 0, 0);
                acc[i][0] = __builtin_amdgcn_mfma_f32_32x32x16_f16(alf, bf0,  acc[i][0], 0, 0, 0);
                acc[i][1] = __builtin_amdgcn_mfma_f32_32x32x16_f16(af,  bf1,  acc[i][1], 0, 0, 0);
                acc[i][1] = __builtin_amdgcn_mfma_f32_32x32x16_f16(af,  blf1, acc[i][1], 0, 0, 0);
                acc[i][1] = __builtin_amdgcn_mfma_f32_32x32x16_f16(alf, bf1,  acc[i][1], 0, 0, 0);
            }
        }
        __syncthreads();
    }

    const float sqj0 = SQb[j0 + wc + lr];
    const float sqj1 = SQb[j0 + wc + 32 + lr];
    #pragma unroll
    for (int i = 0; i < 2; ++i) {
        #pragma unroll
        for (int r = 0; r < 16; ++r) {
            const int row = wr + i * 32 + (r & 3) + 8 * (r >> 2) + 4 * hsel;
            const float sqi = SQb[i0 + row];
            float* out = DTb + (size_t)(i0 + row) * NPTS + j0 + wc;
            out[lr]      = (sqi + sqj0) - 2.f * acc[i][0][r];
            out[32 + lr] = (sqi + sqj1) - 2.f * acc[i][1][r];
        }
    }
}

// ---------------- knn select: one query per wave, dists in registers ----------------
__global__ __launch_bounds__(256) void knn_select_kernel(const float* __restrict__ DT,
                                                         int* __restrict__ IDX, int qoff) {
    const int t = threadIdx.x;
    const int w = t >> 6, lane = t & 63;
    const int q = blockIdx.x * 4 + w;
    const float* dq = DT + (size_t)q * NPTS;
    const int l4 = lane << 2;

    float vals[32];
    #pragma unroll
    for (int s = 0; s < 8; ++s) {
        float4 v = *(const float4*)(dq + s * 256 + l4);
        vals[s * 4 + 0] = v.x; vals[s * 4 + 1] = v.y;
        vals[s * 4 + 2] = v.z; vals[s * 4 + 3] = v.w;
    }
    unsigned rm = 0;
    float best = INFINITY; int bslot = 32;
    #pragma unroll
    for (int sl = 0; sl < 32; ++sl)
        if (vals[sl] < best) { best = vals[sl]; bslot = sl; }

    for (int rep = 0; rep < KNN; ++rep) {
        int bj = (bslot < 32) ? ((bslot >> 2) * 256 + l4 + (bslot & 3)) : NPTS;
        float gb = best; int gj = bj;
        #pragma unroll
        for (int off = 1; off < 64; off <<= 1) {
            float ov = __shfl_xor(gb, off);
            int oj = __shfl_xor(gj, off);
            if (ov < gb || (ov == gb && oj < gj)) { gb = ov; gj = oj; }
        }
        if (lane == 0) IDX[(size_t)(qoff + q) * KNN + rep] = gj;
        if (((gj >> 2) & 63) == lane) {
            int slot = ((gj >> 8) << 2) | (gj & 3);
            rm |= (1u << slot);
            best = INFINITY; bslot = 32;
            #pragma unroll
            for (int sl = 0; sl < 32; ++sl)
                if (!(rm & (1u << sl)) && vals[sl] < best) { best = vals[sl]; bslot = sl; }
        }
    }
}

// ---------------- gemm big: C[M,N] = A[M,K]@B[K,N] + bias, 128x128, BK=32, plain -----
template <int KK, int NN>
__global__ __launch_bounds__(256) void gemm_big_kernel(const float* __restrict__ A,
                                                       const float* __restrict__ B,
                                                       const float* __restrict__ bias,
                                                       float* __restrict__ C) {
    __shared__ float As[32][132];
    __shared__ float Bs[32][132];
    const int t = threadIdx.x;
    const int tx = t & 15, ty = t >> 4;
    const int m0 = blockIdx.x * 128;
    const int c0 = blockIdx.y * 128;

    float acc[8][8];
    #pragma unroll
    for (int i = 0; i < 8; ++i)
        #pragma unroll
        for (int j = 0; j < 8; ++j) acc[i][j] = 0.f;

    const int e = t & 127;
    const int rh = (t >> 7) * 16;
    const float* Ar = A + (size_t)(m0 + e) * KK + rh;
    const int br = t & 31;
    const int bc = (t >> 5) * 16;
    const float* Wbase = B + (size_t)br * NN + c0 + bc;

    for (int k0 = 0; k0 < KK; k0 += 32) {
        #pragma unroll
        for (int h = 0; h < 4; ++h) {
            float4 a = *(const float4*)(Ar + k0 + h * 4);
            As[rh + h * 4 + 0][e] = a.x; As[rh + h * 4 + 1][e] = a.y;
            As[rh + h * 4 + 2][e] = a.z; As[rh + h * 4 + 3][e] = a.w;
            *(float4*)&Bs[br][bc + h * 4] = *(const float4*)(Wbase + (size_t)k0 * NN + h * 4);
        }
        __syncthreads();
        #pragma unroll
        for (int r = 0; r < 32; ++r) {
            float4 a0 = *(const float4*)&As[r][ty * 4];
            float4 a1 = *(const float4*)&As[r][64 + ty * 4];
            float4 b0 = *(const float4*)&Bs[r][tx * 4];
            float4 b1 = *(const float4*)&Bs[r][64 + tx * 4];
            float av[8] = {a0.x, a0.y, a0.z, a0.w, a1.x, a1.y, a1.z, a1.w};
            float bv[8] = {b0.x, b0.y, b0.z, b0.w, b1.x, b1.y, b1.z, b1.w};
            #pragma unroll
            for (int i = 0; i < 8; ++i)
                #pragma unroll
                for (int j = 0; j < 8; ++j)
                    acc[i][j] = fmaf(av[i], bv[j], acc[i][j]);
        }
        __syncthreads();
    }

    float bvv[8];
    #pragma unroll
    for (int j = 0; j < 8; ++j) {
        int co = (j < 4) ? (tx * 4 + j) : (64 + tx * 4 + (j - 4));
        bvv[j] = bias[c0 + co];
    }
    #pragma unroll
    for (int i = 0; i < 8; ++i) {
        int ro = (i < 4) ? (ty * 4 + i) : (64 + ty * 4 + (i - 4));
        float* out = C + (size_t)(m0 + ro) * NN + c0;
        float4 o0, o1;
        o0.x = acc[i][0] + bvv[0]; o0.y = acc[i][1] + bvv[1];
        o0.z = acc[i][2] + bvv[2]; o0.w = acc[i][3] + bvv[3];
        o1.x = acc[i][4] + bvv[4]; o1.y = acc[i][5] + bvv[5];
        o1.z = acc[i][6] + bvv[6]; o1.w = acc[i][7] + bvv[7];
        *(float4*)(out + tx * 4) = o0;
        *(float4*)(out + 64 + tx * 4) = o1;
    }
}

// ---------------- generic tiled GEMM (fallback, 64x64): C = A@B + bias ----------------
template <int KK, int NN>
__global__ __launch_bounds__(256) void gemm_pq_kernel(const float* __restrict__ A,
                                                      const float* __restrict__ B,
                                                      const float* __restrict__ bias,
                                                      float* __restrict__ C) {
    __shared__ float As[16][68];
    __shared__ float Bs[16][64];
    const int t = threadIdx.x;
    const int tx = t & 15, ty = t >> 4;
    const int m0 = blockIdx.x * 64;
    const int c0 = blockIdx.y * 64;
    float acc[4][4];
    #pragma unroll
    for (int i = 0; i < 4; ++i)
        #pragma unroll
        for (int j = 0; j < 4; ++j) acc[i][j] = 0.f;

    constexpr int KCH = (KK + 15) / 16;
    for (int kc = 0; kc < KCH; ++kc) {
        const int k0 = kc * 16;
        {
            int m = t & 63;
            int r4 = (t >> 6) * 4;
            if constexpr (KK % 16 == 0) {
                float4 v = *(const float4*)(A + (size_t)(m0 + m) * KK + k0 + r4);
                As[r4 + 0][m] = v.x; As[r4 + 1][m] = v.y;
                As[r4 + 2][m] = v.z; As[r4 + 3][m] = v.w;
            } else {
                #pragma unroll
                for (int i = 0; i < 4; ++i) {
                    int r = r4 + i;
                    As[r][m] = (k0 + r < KK) ? A[(size_t)(m0 + m) * KK + k0 + r] : 0.f;
                }
            }
        }
        {
            int r = t >> 4;
            int c = (t & 15) * 4;
            float4 v = make_float4(0.f, 0.f, 0.f, 0.f);
            if (k0 + r < KK) v = *(const float4*)(B + (size_t)(k0 + r) * NN + c0 + c);
            *(float4*)&Bs[r][c] = v;
        }
        __syncthreads();
        #pragma unroll
        for (int r = 0; r < 16; ++r) {
            float4 a4 = *(const float4*)&As[r][ty * 4];
            float4 b4 = *(const float4*)&Bs[r][tx * 4];
            float av[4] = {a4.x, a4.y, a4.z, a4.w};
            float bv[4] = {b4.x, b4.y, b4.z, b4.w};
            #pragma unroll
            for (int i = 0; i < 4; ++i)
                #pragma unroll
                for (int j = 0; j < 4; ++j)
                    acc[i][j] = fmaf(av[i], bv[j], acc[i][j]);
        }
        __syncthreads();
    }
    float4 bv4 = *(const float4*)(bias + c0 + tx * 4);
    float bv[4] = {bv4.x, bv4.y, bv4.z, bv4.w};
    #pragma unroll
    for (int i = 0; i < 4; ++i) {
        float4 o;
        o.x = acc[i][0] + bv[0];
        o.y = acc[i][1] + bv[1];
        o.z = acc[i][2] + bv[2];
        o.w = acc[i][3] + bv[3];
        *(float4*)(C + (size_t)(m0 + ty * 4 + i) * NN + c0 + tx * 4) = o;
    }
}

// ---------------- edge small (DOUT<=32): 64 edges x 64 cols, 4x4/thread ----------
template <int D2, int DOUT>
__global__ __launch_bounds__(256) void edge_kernel(const float* __restrict__ PQ,
                                                   const int* __restrict__ IDX,
                                                   const float* __restrict__ W2,
                                                   const float* __restrict__ b2,
                                                   float* __restrict__ Xn) {
    constexpr int N4 = 2 * D2;
    __shared__ float As[16][68];
    __shared__ float Bs[16][64];
    __shared__ int gjs[64];
    const int t = threadIdx.x;
    const int tx = t & 15, ty = t >> 4;
    const int nb = blockIdx.x * 4;
    const int c0 = blockIdx.y * 64;

    if (t < 64) {
        int node = nb + (t >> 4);
        int bstart = (node / NPTS) * NPTS;
        gjs[t] = bstart + IDX[(size_t)node * KNN + (t & 15)];
    }
    __syncthreads();

    float acc[4][4];
    #pragma unroll
    for (int i = 0; i < 4; ++i)
        #pragma unroll
        for (int j = 0; j < 4; ++j) acc[i][j] = 0.f;

    const int e = t & 63;
    const int r4 = (t >> 6) * 4;
    const int gi = nb + (e >> 4);

    for (int k0 = 0; k0 < D2; k0 += 16) {
        {
            int gj = gjs[e];
            float4 p = *(const float4*)(PQ + (size_t)gi * N4 + k0 + r4);
            float4 q = *(const float4*)(PQ + (size_t)gj * N4 + D2 + k0 + r4);
            As[r4 + 0][e] = fmaxf(p.x + q.x, 0.f);
            As[r4 + 1][e] = fmaxf(p.y + q.y, 0.f);
            As[r4 + 2][e] = fmaxf(p.z + q.z, 0.f);
            As[r4 + 3][e] = fmaxf(p.w + q.w, 0.f);
        }
        {
            int r = t >> 4;
            int c = (t & 15) * 4;
            float4 v = make_float4(0.f, 0.f, 0.f, 0.f);
            if (c0 + c < DOUT) v = *(const float4*)(W2 + (size_t)(k0 + r) * DOUT + c0 + c);
            *(float4*)&Bs[r][c] = v;
        }
        __syncthreads();
        #pragma unroll
        for (int r = 0; r < 16; ++r) {
            float4 a4 = *(const float4*)&As[r][ty * 4];
            float4 b4 = *(const float4*)&Bs[r][tx * 4];
            float av[4] = {a4.x, a4.y, a4.z, a4.w};
            float bv[4] = {b4.x, b4.y, b4.z, b4.w};
            #pragma unroll
            for (int i = 0; i < 4; ++i)
                #pragma unroll
                for (int j = 0; j < 4; ++j)
                    acc[i][j] = fmaf(av[i], bv[j], acc[i][j]);
        }
        __syncthreads();
    }

    float bv[4];
    #pragma unroll
    for (int j = 0; j < 4; ++j) {
        int c = c0 + tx * 4 + j;
        bv[j] = (c < DOUT) ? b2[c] : 0.f;
    }
    float s[4];
    #pragma unroll
    for (int j = 0; j < 4; ++j) {
        float ss = 0.f;
        #pragma unroll
        for (int i = 0; i < 4; ++i) ss += fmaxf(acc[i][j] + bv[j], 0.f);
        s[j] = ss;
    }
    #pragma unroll
    for (int j = 0; j < 4; ++j) Bs[ty][tx * 4 + j] = s[j];
    __syncthreads();
    if ((ty & 3) == 0) {
        int node = nb + (ty >> 2);
        #pragma unroll
        for (int j = 0; j < 4; ++j) {
            int c = c0 + tx * 4 + j;
            if (c < DOUT) {
                int cc = tx * 4 + j;
                float tot = Bs[ty][cc] + Bs[ty + 1][cc] + Bs[ty + 2][cc] + Bs[ty + 3][cc];
                Xn[(size_t)node * DOUT + c] = tot * (1.f / 16.f);
            }
        }
    }
}

// ======== edge big (DOUT>=128): f16x3 MFMA, A+B LDS DOUBLE-BUFFER, 1 barrier/K-step ==
// (round-8 verified best configuration: 311us, MfmaUtil 29.5%, total 1728)
#define EBG_LOAD(KN)                                                                 \
  { _Pragma("unroll")                                                                \
    for (int h = 0; h < 4; ++h) {                                                    \
      pp[h] = *(const float4*)(Prow + (KN) + rh + h * 4);                            \
      qq[h] = *(const float4*)(Qrow + (KN) + rh + h * 4);                            \
    }                                                                                \
    wh = *(const half8*)(WHrow + (KN));                                              \
    wl = *(const half8*)(WLrow + (KN)); }

#define EBG_STAGE(dst)                                                               \
  { _Pragma("unroll")                                                                \
    for (int h = 0; h < 4; ++h) {                                                    \
      float a0 = fmaxf(pp[h].x + qq[h].x, 0.f);                                      \
      float a1 = fmaxf(pp[h].y + qq[h].y, 0.f);                                      \
      float a2 = fmaxf(pp[h].z + qq[h].z, 0.f);                                      \
      float a3 = fmaxf(pp[h].w + qq[h].w, 0.f);                                      \
      _Float16 h0 = (_Float16)a0, h1 = (_Float16)a1;                                 \
      _Float16 h2 = (_Float16)a2, h3 = (_Float16)a3;                                 \
      half4 hv, lv;                                                                  \
      hv.x = h0; hv.y = h1; hv.z = h2; hv.w = h3;                                    \
      lv.x = (_Float16)(a0 - (float)h0);                                             \
      lv.y = (_Float16)(a1 - (float)h1);                                             \
      lv.z = (_Float16)(a2 - (float)h2);                                             \
      lv.w = (_Float16)(a3 - (float)h3);                                             \
      *(half4*)&Ah[dst][e][rh + h * 4] = hv;                                         \
      *(half4*)&Al[dst][e][rh + h * 4] = lv;                                         \
    }                                                                                \
    *(half8*)&Bh[dst][eb][rb] = wh;                                                  \
    *(half8*)&Bl[dst][eb][rb] = wl; }

#define EBG_MFMA(cur)                                                                \
  { _Pragma("unroll")                                                                \
    for (int ks = 0; ks < 2; ++ks) {                                                 \
      const int kb = ks * 16 + lk;                                                   \
      half8 bf0  = *(const half8*)&Bh[cur][wc + lr][kb];                             \
      half8 blf0 = *(const half8*)&Bl[cur][wc + lr][kb];                             \
      half8 bf1  = *(const half8*)&Bh[cur][wc + 32 + lr][kb];                        \
      half8 blf1 = *(const half8*)&Bl[cur][wc + 32 + lr][kb];                        \
      _Pragma("unroll")                                                              \
      for (int i = 0; i < 2; ++i) {                                                  \
        half8 af  = *(const half8*)&Ah[cur][wr + i * 32 + lr][kb];                   \
        half8 alf = *(const half8*)&Al[cur][wr + i * 32 + lr][kb];                   \
        acc[i][0] = __builtin_amdgcn_mfma_f32_32x32x16_f16(af,  bf0,  acc[i][0], 0, 0, 0); \
        acc[i][0] = __builtin_amdgcn_mfma_f32_32x32x16_f16(af,  blf0, acc[i][0], 0, 0, 0); \
        acc[i][0] = __builtin_amdgcn_mfma_f32_32x32x16_f16(alf, bf0,  acc[i][0], 0, 0, 0); \
        acc[i][1] = __builtin_amdgcn_mfma_f32_32x32x16_f16(af,  bf1,  acc[i][1], 0, 0, 0); \
        acc[i][1] = __builtin_amdgcn_mfma_f32_32x32x16_f16(af,  blf1, acc[i][1], 0, 0, 0); \
        acc[i][1] = __builtin_amdgcn_mfma_f32_32x32x16_f16(alf, bf1,  acc[i][1], 0, 0, 0); \
      }                                                                              \
    } }

template <int D2, int DOUT>
__global__ __launch_bounds__(512) void edge_big_mfma_kernel(const float* __restrict__ PQ,
                                                            const int* __restrict__ IDX,
                                                            const _Float16* __restrict__ W2H,
                                                            const _Float16* __restrict__ W2L,
                                                            const float* __restrict__ b2,
                                                            float* __restrict__ Xn) {
    constexpr int N4 = 2 * D2;
    constexpr int NSTEP = D2 / 32;
    __shared__ _Float16 Ah[2][256][40];
    __shared__ _Float16 Al[2][256][40];
    __shared__ _Float16 Bh[2][128][40];
    __shared__ _Float16 Bl[2][128][40];
    __shared__ int gjs[256];
    const int t = threadIdx.x;
    const int nb16 = blockIdx.x * 16;
    const int c0 = blockIdx.y * 128;

    if (t < 256) {
        int node = nb16 + (t >> 4);
        int bstart = (node / NPTS) * NPTS;
        gjs[t] = bstart + IDX[(size_t)node * KNN + (t & 15)];
    }
    __syncthreads();

    const int e  = t & 255;
    const int rh = (t >> 8) * 16;
    const int gi = nb16 + (e >> 4);
    const int gj = gjs[e];
    const float* Prow = PQ + (size_t)gi * N4;
    const float* Qrow = PQ + (size_t)gj * N4 + D2;
    const int eb = t & 127;
    const int rb = (t >> 7) * 8;
    const _Float16* WHrow = W2H + (size_t)(c0 + eb) * D2 + rb;
    const _Float16* WLrow = W2L + (size_t)(c0 + eb) * D2 + rb;

    const int w = t >> 6;
    const int lane = t & 63;
    const int wr = (w >> 1) * 64;
    const int wc = (w & 1) * 64;
    const int lr = lane & 31;
    const int lk = (lane >> 5) * 8;
    const int hsel = lane >> 5;

    floatx16 acc[2][2];
    #pragma unroll
    for (int i = 0; i < 2; ++i)
        #pragma unroll
        for (int j = 0; j < 2; ++j)
            #pragma unroll
            for (int r = 0; r < 16; ++r) acc[i][j][r] = 0.f;

    float4 pp[4], qq[4];
    half8 wh, wl;

    EBG_LOAD(0)
    EBG_STAGE(0)
    EBG_LOAD(32)
    asm volatile("s_waitcnt lgkmcnt(0)" ::: "memory");
    __builtin_amdgcn_s_barrier();
    asm volatile("" ::: "memory");

    for (int s = 0; s < NSTEP - 1; ++s) {
        const int cur = s & 1;
        EBG_MFMA(cur)
        EBG_STAGE(cur ^ 1)
        const int kn = (s + 2 < NSTEP) ? (s + 2) * 32 : (NSTEP - 1) * 32;
        EBG_LOAD(kn)
        asm volatile("s_waitcnt lgkmcnt(0)" ::: "memory");
        __builtin_amdgcn_s_barrier();
        asm volatile("" ::: "memory");
    }
    EBG_MFMA((NSTEP - 1) & 1)

    float bb[2];
    bb[0] = b2[c0 + wc + lr];
    bb[1] = b2[c0 + wc + 32 + lr];
    #pragma unroll
    for (int i = 0; i < 2; ++i) {
        int node0 = nb16 + ((wr + i * 32) >> 4);
        #pragma unroll
        for (int j = 0; j < 2; ++j) {
            float sA = 0.f, sB = 0.f;
            #pragma unroll
            for (int r = 0; r < 8; ++r)  sA += fmaxf(acc[i][j][r] + bb[j], 0.f);
            #pragma unroll
            for (int r = 8; r < 16; ++r) sB += fmaxf(acc[i][j][r] + bb[j], 0.f);
            sA += __shfl_xor(sA, 32);
            sB += __shfl_xor(sB, 32);
            if (hsel == 0) {
                int col = c0 + wc + j * 32 + lr;
                Xn[(size_t)node0 * DOUT + col] = sA * (1.f / 16.f);
                Xn[(size_t)(node0 + 1) * DOUT + col] = sB * (1.f / 16.f);
            }
        }
    }
}
#undef EBG_LOAD
#undef EBG_STAGE
#undef EBG_MFMA

// ======== edge mid (DOUT==64): f16x3 MFMA, round-4 depth-2 pipeline, 64x32/wave =====
// (31 KB LDS -> 5 blocks/CU; occupancy beats dbuf depth at this size)
#define EM_STAGE_MFMA(KC, QQ, POK, KP)                                               \
  {                                                                                  \
    half8 wh0 = *(const half8*)(WHrow + (KC));                                       \
    half8 wl0 = *(const half8*)(WLrow + (KC));                                       \
    _Pragma("unroll")                                                                \
    for (int h = 0; h < 4; ++h) {                                                    \
      float4 p = *(const float4*)(Prow + (KC) + rh + h * 4);                         \
      float a0 = fmaxf(p.x + QQ[h].x, 0.f);                                          \
      float a1 = fmaxf(p.y + QQ[h].y, 0.f);                                          \
      float a2 = fmaxf(p.z + QQ[h].z, 0.f);                                          \
      float a3 = fmaxf(p.w + QQ[h].w, 0.f);                                          \
      _Float16 h0 = (_Float16)a0, h1 = (_Float16)a1;                                 \
      _Float16 h2 = (_Float16)a2, h3 = (_Float16)a3;                                 \
      half4 hv, lv;                                                                  \
      hv.x = h0; hv.y = h1; hv.z = h2; hv.w = h3;                                    \
      lv.x = (_Float16)(a0 - (float)h0);                                             \
      lv.y = (_Float16)(a1 - (float)h1);                                             \
      lv.z = (_Float16)(a2 - (float)h2);                                             \
      lv.w = (_Float16)(a3 - (float)h3);                                             \
      *(half4*)&Ah[e][rh + h * 4] = hv;                                              \
      *(half4*)&Al[e][rh + h * 4] = lv;                                              \
    }                                                                                \
    *(half8*)&Bh[wrB][wkB] = wh0;                                                    \
    *(half8*)&Bl[wrB][wkB] = wl0;                                                    \
    if (POK) {                                                                       \
      _Pragma("unroll")                                                              \
      for (int h = 0; h < 4; ++h)                                                    \
        QQ[h] = *(const float4*)(Qrow + (KP) + rh + h * 4);                          \
    }                                                                                \
    asm volatile("s_waitcnt lgkmcnt(0)" ::: "memory");                               \
    __builtin_amdgcn_s_barrier();                                                    \
    asm volatile("" ::: "memory");                                                   \
    _Pragma("unroll")                                                                \
    for (int ks = 0; ks < 2; ++ks) {                                                 \
      const int kb = ks * 16 + lk;                                                   \
      half8 bf0 = *(const half8*)&Bh[wc + lr][kb];                                   \
      half8 blf0 = *(const half8*)&Bl[wc + lr][kb];                                  \
      _Pragma("unroll")                                                              \
      for (int i = 0; i < 2; ++i) {                                                  \
        half8 af = *(const half8*)&Ah[wr + i * 32 + lr][kb];                         \
        half8 alf = *(const half8*)&Al[wr + i * 32 + lr][kb];                        \
        acc[i] = __builtin_amdgcn_mfma_f32_32x32x16_f16(af, bf0, acc[i], 0, 0, 0);   \
        acc[i] = __builtin_amdgcn_mfma_f32_32x32x16_f16(af, blf0, acc[i], 0, 0, 0);  \
        acc[i] = __builtin_amdgcn_mfma_f32_32x32x16_f16(alf, bf0, acc[i], 0, 0, 0);  \
      }                                                                              \
    }                                                                                \
    asm volatile("" ::: "memory");                                                   \
    __builtin_amdgcn_s_barrier();                                                    \
    asm volatile("" ::: "memory");                                                   \
  }

template <int D2, int DOUT>
__global__ __launch_bounds__(256) void edge_mid_mfma_kernel(const float* __restrict__ PQ,
                                                            const int* __restrict__ IDX,
                                                            const _Float16* __restrict__ W2H,
                                                            const _Float16* __restrict__ W2L,
                                                            const float* __restrict__ b2,
                                                            float* __restrict__ Xn) {
    constexpr int N4 = 2 * D2;
    __shared__ _Float16 Ah[128][40];
    __shared__ _Float16 Al[128][40];
    __shared__ _Float16 Bh[64][40];
    __shared__ _Float16 Bl[64][40];
    __shared__ int gjs[128];
    const int t = threadIdx.x;
    const int nb8 = blockIdx.x * 8;

    if (t < 128) {
        int node = nb8 + (t >> 4);
        int bstart = (node / NPTS) * NPTS;
        gjs[t] = bstart + IDX[(size_t)node * KNN + (t & 15)];
    }
    __syncthreads();

    const int e = t & 127;
    const int rh = (t >> 7) * 16;
    const int gi = nb8 + (e >> 4);
    const int gj = gjs[e];
    const float* Prow = PQ + (size_t)gi * N4;
    const float* Qrow = PQ + (size_t)gj * N4 + D2;
    const int wrB = t & 63;
    const int wkB = (t >> 6) * 8;
    const _Float16* WHrow = W2H + (size_t)wrB * D2 + wkB;
    const _Float16* WLrow = W2L + (size_t)wrB * D2 + wkB;

    const int w = t >> 6;
    const int lane = t & 63;
    const int wr = (w >> 1) * 64;
    const int wc = (w & 1) * 32;
    const int lr = lane & 31;
    const int lk = (lane >> 5) * 8;
    const int hsel = lane >> 5;

    floatx16 acc[2];
    #pragma unroll
    for (int i = 0; i < 2; ++i)
        #pragma unroll
        for (int r = 0; r < 16; ++r) acc[i][r] = 0.f;

    float4 qqA[4], qqB[4];
    #pragma unroll
    for (int h = 0; h < 4; ++h) qqA[h] = *(const float4*)(Qrow + rh + h * 4);
    #pragma unroll
    for (int h = 0; h < 4; ++h) qqB[h] = *(const float4*)(Qrow + 32 + rh + h * 4);

    for (int k0 = 0; k0 < D2; k0 += 64) {
        EM_STAGE_MFMA(k0,      qqA, (k0 + 64 < D2), k0 + 64)
        EM_STAGE_MFMA(k0 + 32, qqB, (k0 + 96 < D2), k0 + 96)
    }

    float bb = b2[wc + lr];
    #pragma unroll
    for (int i = 0; i < 2; ++i) {
        int node0 = nb8 + ((wr + i * 32) >> 4);
        float sA = 0.f, sB = 0.f;
        #pragma unroll
        for (int r = 0; r < 8; ++r)  sA += fmaxf(acc[i][r] + bb, 0.f);
        #pragma unroll
        for (int r = 8; r < 16; ++r) sB += fmaxf(acc[i][r] + bb, 0.f);
        sA += __shfl_xor(sA, 32);
        sB += __shfl_xor(sB, 32);
        if (hsel == 0) {
            int col = wc + lr;
            Xn[(size_t)node0 * DOUT + col] = sA * (1.f / 16.f);
            Xn[(size_t)(node0 + 1) * DOUT + col] = sB * (1.f / 16.f);
        }
    }
}
#undef EM_STAGE_MFMA

// ---------------- final: mean over nodes + 16x2 projection ----------------
__global__ __launch_bounds__(256) void final_kernel(const float* __restrict__ X,
                                                    const float* __restrict__ Wf,
                                                    const float* __restrict__ bfin,
                                                    float* __restrict__ out) {
    __shared__ float red[16][17];
    __shared__ float pool[16];
    const int b = blockIdx.x;
    const int t = threadIdx.x;
    const int c = t & 15, rg = t >> 4;
    float s = 0.f;
    for (int n = rg; n < NPTS; n += 16) s += X[(size_t)(b * NPTS + n) * 16 + c];
    red[rg][c] = s;
    __syncthreads();
    if (t < 16) {
        float tot = 0.f;
        #pragma unroll
        for (int i = 0; i < 16; ++i) tot += red[i][t];
        pool[t] = tot * (1.f / NPTS);
    }
    __syncthreads();
    if (t < 2) {
        float a = bfin[t];
        #pragma unroll
        for (int cc = 0; cc < 16; ++cc) a = fmaf(pool[cc], Wf[cc * 2 + t], a);
        out[b * 2 + t] = a;
    }
}

// ---------------- per-layer driver ----------------
template <int DIN, int DOUT>
static void run_layer(const float* Xin, float* Xout, float* PQ, float* SQ, int* IDX,
                      float* WCAT, float* BCAT, _Float16* W2H, _Float16* W2L,
                      const float* W1, const float* b1, const float* W2, const float* b2,
                      hipStream_t stream) {
    constexpr int D2 = 2 * DOUT;
    constexpr int N4 = 2 * D2;
    constexpr int prep_blocks = (DIN * N4 + 255) / 256;
    constexpr int w2_blocks = (DOUT >= 64) ? ((D2 * DOUT + 255) / 256) : 0;
    sqprep_kernel<<<BN / 256 + prep_blocks + w2_blocks, 256, 0, stream>>>(
        Xin, SQ, W1, b1, WCAT, BCAT, DIN, D2, W2, W2H, W2L,
        (DOUT >= 64) ? DOUT : 0, prep_blocks);
    for (int h = 0; h < 2; ++h) {
        if constexpr (DIN % 32 == 0) {
            dim3 gg(256, 1, 4);   // full 16x16 tile grid, coalesced writes
            gram_mfma_kernel<DIN><<<gg, 256, 0, stream>>>(Xin + (size_t)h * 4 * NPTS * DIN,
                                                          SQ + (size_t)h * 4 * NPTS, PQ);
        } else {
            dim3 gg(136, 1, 4);   // triangular fp32 path (DIN=3)
            gram_kernel<DIN><<<gg, 256, 0, stream>>>(Xin + (size_t)h * 4 * NPTS * DIN,
                                                     SQ + (size_t)h * 4 * NPTS, PQ);
        }
        knn_select_kernel<<<2048, 256, 0, stream>>>(PQ, IDX, h * 8192);
    }
    if constexpr (N4 % 128 == 0 && DIN % 32 == 0) {
        dim3 g1(BN / 128, N4 / 128);
        gemm_big_kernel<DIN, N4><<<g1, 256, 0, stream>>>(Xin, WCAT, BCAT, PQ);
    } else {
        dim3 g1(BN / 64, N4 / 64);
        gemm_pq_kernel<DIN, N4><<<g1, 256, 0, stream>>>(Xin, WCAT, BCAT, PQ);
    }
    if constexpr (DOUT >= 128) {
        dim3 g2(BN / 16, DOUT / 128);
        edge_big_mfma_kernel<D2, DOUT><<<g2, 512, 0, stream>>>(PQ, IDX, W2H, W2L, b2, Xout);
    } else if constexpr (DOUT == 64) {
        dim3 g2(BN / 8, 1);
        edge_mid_mfma_kernel<D2, DOUT><<<g2, 256, 0, stream>>>(PQ, IDX, W2H, W2L, b2, Xout);
    } else {
        dim3 g2(BN / 4, (DOUT + 63) / 64);
        edge_kernel<D2, DOUT><<<g2, 256, 0, stream>>>(PQ, IDX, W2, b2, Xout);
    }
}

extern "C" void kernel_launch(void* const* d_in, const int* in_sizes, int n_in,
                              void* d_out, int out_size, void* d_ws, size_t ws_size,
                              hipStream_t stream) {
    (void)in_sizes; (void)n_in; (void)out_size; (void)ws_size;
    const float* x = (const float*)d_in[0];
    const float* W1a[6]; const float* b1a[6]; const float* W2a[6]; const float* b2a[6];
    for (int l = 0; l < 6; ++l) {
        W1a[l] = (const float*)d_in[1 + 4 * l];
        b1a[l] = (const float*)d_in[2 + 4 * l];
        W2a[l] = (const float*)d_in[3 + 4 * l];
        b2a[l] = (const float*)d_in[4 + 4 * l];
    }
    const float* Wf = (const float*)d_in[25];
    const float* bfin = (const float*)d_in[26];

    float* ws = (float*)d_ws;
    float* X0   = ws;                                   // 16384*256
    float* X1   = X0 + (size_t)BN * 256;                // 16384*256
    float* PQ   = X1 + (size_t)BN * 256;                // 16384*1024 (also knn DT)
    float* SQ   = PQ + (size_t)BN * 1024;               // 16384
    int*   IDX  = (int*)(SQ + BN);                      // 16384*16
    float* WCAT = (float*)(IDX + (size_t)BN * KNN);     // 131072
    float* BCAT = WCAT + 131072;                        // 1024
    _Float16* W2H = (_Float16*)(BCAT + 1024);           // 131072 halfs (256 KB)
    _Float16* W2L = W2H + 131072;                       // 131072 halfs (256 KB)

    run_layer<3,   32>(x,  X0, PQ, SQ, IDX, WCAT, BCAT, W2H, W2L, W1a[0], b1a[0], W2a[0], b2a[0], stream);
    run_layer<32, 128>(X0, X1, PQ, SQ, IDX, WCAT, BCAT, W2H, W2L, W1a[1], b1a[1], W2a[1], b2a[1], stream);
    run_layer<128,256>(X1, X0, PQ, SQ, IDX, WCAT, BCAT, W2H, W2L, W1a[2], b1a[2], W2a[2], b2a[2], stream);
    run_layer<256, 64>(X0, X1, PQ, SQ, IDX, WCAT, BCAT, W2H, W2L, W1a[3], b1a[3], W2a[3], b2a[3], stream);
    run_layer<64,  32>(X1, X0, PQ, SQ, IDX, WCAT, BCAT, W2H, W2L, W1a[4], b1a[4], W2a[4], b2a[4], stream);
    run_layer<32,  16>(X0, X1, PQ, SQ, IDX, WCAT, BCAT, W2H, W2L, W1a[5], b1a[5], W2a[5], b2a[5], stream);
    final_kernel<<<NB, 256, 0, stream>>>(X1, Wf, bfin, (float*)d_out);
}